// Round 4
// baseline (820.334 us; speedup 1.0000x reference)
//
#include <hip/hip_runtime.h>
#include <hip/hip_bf16.h>

// Problem constants: B=4, N=2048, D=1024, H=16, dh=64. All I/O fp32.
#define SEQ   2048
#define DIM   1024
#define HEADS 16
#define DH    64
#define MROWS 8192            // B*N
#define K3    3072            // 3*D
#define NEGV  (-32767.0f)     // -2^15+1, matches reference mask constant
#define SCALE 8.0f            // sqrt(dh) — reference MULTIPLIES by sqrt(d)

typedef __attribute__((ext_vector_type(8))) short bf16x8;
typedef __attribute__((ext_vector_type(4))) float f32x4;

// bf16 round-to-nearest-even via bit ops (finite inputs only)
__device__ __forceinline__ short f2bf(float x) {
  union { float f; unsigned u; } v; v.f = x;
  unsigned r = v.u + 0x7FFF + ((v.u >> 16) & 1);
  return (short)(r >> 16);
}
__device__ __forceinline__ float bf2f(short s) {
  union { float f; unsigned u; } v; v.u = ((unsigned)(unsigned short)s) << 16;
  return v.f;
}
__device__ __forceinline__ void split1(float x, short& h, short& l) {
  h = f2bf(x);
  l = f2bf(x - bf2f(h));
}
__device__ __forceinline__ void cvt_split8(const float4 a, const float4 b,
                                           bf16x8& hi, bf16x8& lo) {
  const float f[8] = {a.x, a.y, a.z, a.w, b.x, b.y, b.z, b.w};
#pragma unroll
  for (int i = 0; i < 8; i++) {
    short h, l; split1(f[i], h, l);
    hi[i] = h; lo[i] = l;
  }
}

// async global->LDS, 16B per lane. LDS dest is wave-uniform base; HW writes
// lane l at base + l*16 bytes. Global src is per-lane.
__device__ __forceinline__ void glds16(const void* g, void* l) {
  __builtin_amdgcn_global_load_lds(
      (const __attribute__((address_space(1))) void*)g,
      (__attribute__((address_space(3))) void*)l, 16, 0, 0);
}

// XOR-swizzled LDS index (shorts) for 64-col row-major tiles: 8-short (16B)
// blocks permuted by row&7 -> ds_read_b128-able fragments, spread banks.
__device__ __forceinline__ int sw(int row, int col) {
  return row * 64 + ((((col >> 3) ^ row) & 7) << 3) + (col & 7);
}

// ---------------------------------------------------------------------------
// Prep kernels: one-time fp32 -> bf16 (hi/lo RNE split where needed).
// ---------------------------------------------------------------------------
__global__ __launch_bounds__(256) void prep_x(
    const float* __restrict__ q, const float* __restrict__ k,
    const float* __restrict__ v,
    short* __restrict__ ah, short* __restrict__ al)  // (8192, 3072) bf16 each
{
  const int n = MROWS * (K3 / 4);                    // float4 work items
  for (int i = blockIdx.x * 256 + threadIdx.x; i < n; i += gridDim.x * 256) {
    const int r  = i / 768;                          // 3072/4 cols per row
    const int c4 = i - r * 768;
    const float* src = (c4 < 256) ? q : ((c4 < 512) ? k : v);
    const int cc = c4 & 255;
    const float4 f = *(const float4*)(src + ((size_t)r * 256 + cc) * 4);
    const float fa[4] = {f.x, f.y, f.z, f.w};
    short hi[4], lo[4];
#pragma unroll
    for (int e = 0; e < 4; ++e) split1(fa[e], hi[e], lo[e]);
    const size_t o = (size_t)r * K3 + c4 * 4;
    *(short4*)(ah + o) = make_short4(hi[0], hi[1], hi[2], hi[3]);
    *(short4*)(al + o) = make_short4(lo[0], lo[1], lo[2], lo[3]);
  }
}

__global__ __launch_bounds__(256) void prep_w(
    const float* __restrict__ w,                     // (3072,3072) fp32
    short* __restrict__ bh, short* __restrict__ bl)  // bf16 each
{
  const int n = (K3 * K3) / 4;
  for (int i = blockIdx.x * 256 + threadIdx.x; i < n; i += gridDim.x * 256) {
    const float4 f = ((const float4*)w)[i];
    const float fa[4] = {f.x, f.y, f.z, f.w};
    short hi[4], lo[4];
#pragma unroll
    for (int e = 0; e < 4; ++e) split1(fa[e], hi[e], lo[e]);
    ((short4*)bh)[i] = make_short4(hi[0], hi[1], hi[2], hi[3]);
    ((short4*)bl)[i] = make_short4(lo[0], lo[1], lo[2], lo[3]);
  }
}

__global__ __launch_bounds__(256) void prep_wo(
    const float* __restrict__ w,                     // (1024,1024) fp32
    short* __restrict__ wb)                          // bf16
{
  const int n = (DIM * DIM) / 4;
  for (int i = blockIdx.x * 256 + threadIdx.x; i < n; i += gridDim.x * 256) {
    const float4 f = ((const float4*)w)[i];
    ((short4*)wb)[i] = make_short4(f2bf(f.x), f2bf(f.y), f2bf(f.z), f2bf(f.w));
  }
}

// ---------------------------------------------------------------------------
// Kernel 1a: qkv GEMM, 256x256 tiles, 8-phase counted-vmcnt schedule.
// Grid = 256 blocks; each block computes ONE heavy (q,k cols; packed-K 144
// tiles) 256x256 tile, then HALF of one light (v cols; 48 tiles) 256-wide
// tile (128 rows) -> uniform 168 tile-equivalents per block (load-balanced).
// ---------------------------------------------------------------------------
__device__ __forceinline__ void stage_half(const short* __restrict__ src,
                                           short* dst, int wv, int lane) {
  // half-tile = 128 rows x 64 cols bf16 = 16KB; wave wv covers 2x1KB pieces.
  // LDS dest linear; source col-block pre-swizzled (involution cb^row&7).
#pragma unroll
  for (int e = 0; e < 2; ++e) {
    const int idx = (wv * 2 + e) * 512 + lane * 8;   // linear short index
    const int row = idx >> 6;
    const int cb  = (idx >> 3) & 7;
    const int cbs = (cb ^ row) & 7;
    glds16(src + (size_t)row * K3 + cbs * 8, dst + (wv * 2 + e) * 512);
  }
}

__global__ __launch_bounds__(512, 2) void qkv_gemm_8p(
    const short* __restrict__ Ah, const short* __restrict__ Al,
    const short* __restrict__ Bh, const short* __restrict__ Bl,
    const float* __restrict__ bqkv,
    short* __restrict__ qh, short* __restrict__ ql)
{
  __shared__ short L[2][4][8192];   // [buf][A0,A1,B0,B1][128*64], 128 KB

  const int t    = threadIdx.x;
  const int lane = t & 63;
  const int wv   = t >> 6;          // 0..7
  const int wr   = wv >> 2;         // 0..1  (M half)
  const int wc   = wv & 3;          // 0..3  (N slice)
  const int l15  = lane & 15;
  const int lq   = lane >> 4;

  // ======================= HEAVY: q,k columns =======================
  // XCD-chunked bijective swizzle over 256 heavy tiles (32 M x 8 N).
  const int w  = (blockIdx.x & 7) * 32 + (blockIdx.x >> 3);
  const int Mb = (w & 31) * 256;
  const int Nb = (w >> 5) * 256;    // 0..1792 (q,k cols)
  const int nt = 144;               // packed-K

  // tile kt -> source for half h (0,1 = A halves; 2,3 = B halves)
  auto tsrc = [&](int kt, int h) -> const short* {
    kt = (kt < nt - 1) ? kt : (nt - 1);
    const int seg = (kt >= 96) ? 2 : ((kt >= 48) ? 1 : 0);
    const int k0  = (kt - seg * 48) * 64;
    if (h < 2) {
      const short* Apl = (seg == 2) ? Al : Ah;
      return Apl + (size_t)(Mb + h * 128) * K3 + k0;
    }
    const short* Bpl = (seg == 1) ? Bl : Bh;
    return Bpl + (size_t)(Nb + (h - 2) * 128) * K3 + k0;
  };

  f32x4 acc[8][4];
#pragma unroll
  for (int i = 0; i < 8; i++)
#pragma unroll
    for (int j = 0; j < 4; j++) acc[i][j] = (f32x4){0.f, 0.f, 0.f, 0.f};

  // prologue: tile 0 -> buf0 (all 4 halves), tile 1 -> buf1 B halves
  stage_half(tsrc(0, 0), &L[0][0][0], wv, lane);
  stage_half(tsrc(0, 1), &L[0][1][0], wv, lane);
  stage_half(tsrc(0, 2), &L[0][2][0], wv, lane);
  stage_half(tsrc(0, 3), &L[0][3][0], wv, lane);
  stage_half(tsrc(1, 2), &L[1][2][0], wv, lane);
  stage_half(tsrc(1, 3), &L[1][3][0], wv, lane);
  asm volatile("s_waitcnt vmcnt(4)" ::: "memory");   // buf0 landed
  __builtin_amdgcn_s_barrier();

  bf16x8 bfr[4][2];                 // B frags, live across each 4-phase group

  for (int kp = 0; kp < nt; kp += 2) {
#pragma unroll
    for (int p = 0; p < 8; ++p) {
      const int buf = p >> 2;
      const int qtr = p & 3;
      const int mi0 = qtr * 2;

      if (qtr == 0) {
#pragma unroll
        for (int ni = 0; ni < 4; ++ni)
#pragma unroll
          for (int ks = 0; ks < 2; ++ks)
            bfr[ni][ks] = *(const bf16x8*)(
                &L[buf][2 + (wc >> 1)][sw((wc & 1) * 64 + ni * 16 + l15,
                                          ks * 32 + lq * 8)]);
      }
      bf16x8 afr[2][2];
#pragma unroll
      for (int m = 0; m < 2; ++m)
#pragma unroll
        for (int ks = 0; ks < 2; ++ks)
          afr[m][ks] = *(const bf16x8*)(
              &L[buf][wr][sw((mi0 + m) * 16 + l15, ks * 32 + lq * 8)]);

      {
        const int SB[8] = {1, 1, 0, 0, 0, 0, 1, 1};
        const int SH[8] = {0, 1, 2, 3, 0, 1, 2, 3};
        const int SD[8] = {1, 1, 2, 2, 2, 2, 3, 3};
        stage_half(tsrc(kp + SD[p], SH[p]), &L[SB[p]][SH[p]][0], wv, lane);
      }

      if (qtr == 3) asm volatile("s_waitcnt vmcnt(4)" ::: "memory");
      __builtin_amdgcn_s_barrier();
      asm volatile("s_waitcnt lgkmcnt(0)" ::: "memory");
      __builtin_amdgcn_sched_barrier(0);

      __builtin_amdgcn_s_setprio(1);
#pragma unroll
      for (int m = 0; m < 2; ++m)
#pragma unroll
        for (int ni = 0; ni < 4; ++ni)
#pragma unroll
          for (int ks = 0; ks < 2; ++ks)
            acc[mi0 + m][ni] = __builtin_amdgcn_mfma_f32_16x16x32_bf16(
                afr[m][ks], bfr[ni][ks], acc[mi0 + m][ni], 0, 0, 0);
      __builtin_amdgcn_s_setprio(0);
      __builtin_amdgcn_s_barrier();
    }
  }

  // heavy epilogue: bias + bf16 hi/lo split output
#pragma unroll
  for (int ni = 0; ni < 4; ++ni) {
    const int col = Nb + wc * 64 + ni * 16 + l15;
    const float bias = bqkv[col];
#pragma unroll
    for (int mi = 0; mi < 8; ++mi) {
#pragma unroll
      for (int r = 0; r < 4; ++r) {
        const int row = Mb + wr * 128 + mi * 16 + lq * 4 + r;
        const float xv = acc[mi][ni][r] + bias;
        const short hh = f2bf(xv);
        qh[(size_t)row * K3 + col] = hh;
        ql[(size_t)row * K3 + col] = f2bf(xv - bf2f(hh));
      }
    }
  }

  // ======================= LIGHT: v columns (half tile) =======================
  asm volatile("s_waitcnt vmcnt(0)" ::: "memory");
  __builtin_amdgcn_s_barrier();

  const int lt  = blockIdx.x >> 1;                   // 0..127 light tiles
  const int MbL = (lt & 31) * 256 + (blockIdx.x & 1) * 128;
  const int NbL = 2 * DIM + (lt >> 5) * 256;

  auto tsrcL = [&](int kt, int h) -> const short* {
    kt = (kt < 47) ? kt : 47;
    const int k0 = kt * 64;
    if (h == 0) return Ah + (size_t)MbL * K3 + k0;
    return Bh + (size_t)(NbL + (h - 2) * 128) * K3 + k0;
  };

#pragma unroll
  for (int i = 0; i < 4; i++)
#pragma unroll
    for (int j = 0; j < 4; j++) acc[i][j] = (f32x4){0.f, 0.f, 0.f, 0.f};

  stage_half(tsrcL(0, 0), &L[0][0][0], wv, lane);
  stage_half(tsrcL(0, 2), &L[0][2][0], wv, lane);
  stage_half(tsrcL(0, 3), &L[0][3][0], wv, lane);
  stage_half(tsrcL(1, 2), &L[1][2][0], wv, lane);
  stage_half(tsrcL(1, 3), &L[1][3][0], wv, lane);
  asm volatile("s_waitcnt vmcnt(4)" ::: "memory");
  __builtin_amdgcn_s_barrier();

  for (int kp = 0; kp < 48; kp += 2) {
#pragma unroll
    for (int p = 0; p < 4; ++p) {
      const int buf = p >> 1;
      const int mh  = p & 1;

      if (mh == 0) {
#pragma unroll
        for (int ni = 0; ni < 4; ++ni)
#pragma unroll
          for (int ks = 0; ks < 2; ++ks)
            bfr[ni][ks] = *(const bf16x8*)(
                &L[buf][2 + (wc >> 1)][sw((wc & 1) * 64 + ni * 16 + l15,
                                          ks * 32 + lq * 8)]);
      }
      bf16x8 afr[2][2];
#pragma unroll
      for (int m = 0; m < 2; ++m)
#pragma unroll
        for (int ks = 0; ks < 2; ++ks)
          afr[m][ks] = *(const bf16x8*)(
              &L[buf][0][sw(wr * 64 + (mh * 2 + m) * 16 + l15,
                            ks * 32 + lq * 8)]);

      if (p == 0) {
        stage_half(tsrcL(kp + 1, 0), &L[1][0][0], wv, lane);
      } else if (p == 1) {
        stage_half(tsrcL(kp + 2, 2), &L[0][2][0], wv, lane);
        stage_half(tsrcL(kp + 2, 3), &L[0][3][0], wv, lane);
      } else if (p == 2) {
        stage_half(tsrcL(kp + 2, 0), &L[0][0][0], wv, lane);
      } else {
        stage_half(tsrcL(kp + 3, 2), &L[1][2][0], wv, lane);
        stage_half(tsrcL(kp + 3, 3), &L[1][3][0], wv, lane);
      }

      if (mh == 1) asm volatile("s_waitcnt vmcnt(4)" ::: "memory");
      __builtin_amdgcn_s_barrier();
      asm volatile("s_waitcnt lgkmcnt(0)" ::: "memory");
      __builtin_amdgcn_sched_barrier(0);

      __builtin_amdgcn_s_setprio(1);
#pragma unroll
      for (int m = 0; m < 2; ++m)
#pragma unroll
        for (int ni = 0; ni < 4; ++ni)
#pragma unroll
          for (int ks = 0; ks < 2; ++ks)
            acc[mh * 2 + m][ni] = __builtin_amdgcn_mfma_f32_16x16x32_bf16(
                afr[m][ks], bfr[ni][ks], acc[mh * 2 + m][ni], 0, 0, 0);
      __builtin_amdgcn_s_setprio(0);
      __builtin_amdgcn_s_barrier();
    }
  }

#pragma unroll
  for (int ni = 0; ni < 4; ++ni) {
    const int col = NbL + wc * 64 + ni * 16 + l15;
    const float bias = bqkv[col];
#pragma unroll
    for (int mi = 0; mi < 4; ++mi) {
#pragma unroll
      for (int r = 0; r < 4; ++r) {
        const int row = MbL + wr * 64 + mi * 16 + lq * 4 + r;
        qh[(size_t)row * K3 + col] = f2bf(acc[mi][ni][r] + bias);
      }
    }
  }
}

// ---------------------------------------------------------------------------
// Kernel 1b (fallback, ws too small for prep): in-loop cvt, hi/lo output.
// ---------------------------------------------------------------------------
__global__ __launch_bounds__(256) void qkv_gemm_fly(
    const float* __restrict__ q,
    const float* __restrict__ k,
    const float* __restrict__ v,
    const float* __restrict__ wqkv,
    const float* __restrict__ bqkv,
    short* __restrict__ qh, short* __restrict__ ql)
{
  __shared__ short Ash[128 * 32];
  __shared__ short Asl[128 * 32];
  __shared__ short Bsh[128 * 32];
  __shared__ short Bsl[128 * 32];

  const int t    = threadIdx.x;
  const int lane = t & 63;
  const int wv   = t >> 6;
  const int Mb   = blockIdx.y * 128;
  const int Nb   = blockIdx.x * 128;
  const bool prec = (Nb < 2 * DIM);
  const int wr   = (wv >> 1) * 64;
  const int wc   = (wv & 1) * 64;
  const int l15  = lane & 15;
  const int lq   = lane >> 4;
  const int srow = wv * 16 + (lane >> 2);
  const int scol = (lane & 3) * 8;

  f32x4 acc[4][4];
#pragma unroll
  for (int i = 0; i < 4; i++)
#pragma unroll
    for (int j = 0; j < 4; j++) acc[i][j] = (f32x4){0.f, 0.f, 0.f, 0.f};

  for (int k0 = 0; k0 < K3; k0 += 32) {
    const float* src = (k0 < DIM) ? q : ((k0 < 2 * DIM) ? k : v);
    const int koff = (k0 & (DIM - 1)) + scol;

    bf16x8 ah[2], al[2], bh[2], bl[2];
#pragma unroll
    for (int it = 0; it < 2; ++it) {
      const float* ap = src + (size_t)(Mb + it * 64 + srow) * DIM + koff;
      cvt_split8(*(const float4*)(ap), *(const float4*)(ap + 4), ah[it], al[it]);
      const float* bp = wqkv + (size_t)(Nb + it * 64 + srow) * K3 + k0 + scol;
      cvt_split8(*(const float4*)(bp), *(const float4*)(bp + 4), bh[it], bl[it]);
    }
    __syncthreads();
#pragma unroll
    for (int it = 0; it < 2; ++it) {
      *(bf16x8*)(Ash + (it * 64 + srow) * 32 + scol) = ah[it];
      *(bf16x8*)(Bsh + (it * 64 + srow) * 32 + scol) = bh[it];
      if (prec) {
        *(bf16x8*)(Asl + (it * 64 + srow) * 32 + scol) = al[it];
        *(bf16x8*)(Bsl + (it * 64 + srow) * 32 + scol) = bl[it];
      }
    }
    __syncthreads();

    bf16x8 afh[4], bfh[4];
#pragma unroll
    for (int i = 0; i < 4; i++)
      afh[i] = *(const bf16x8*)(Ash + (wr + i * 16 + l15) * 32 + lq * 8);
#pragma unroll
    for (int j = 0; j < 4; j++)
      bfh[j] = *(const bf16x8*)(Bsh + (wc + j * 16 + l15) * 32 + lq * 8);
#pragma unroll
    for (int i = 0; i < 4; i++)
#pragma unroll
      for (int j = 0; j < 4; j++)
        acc[i][j] = __builtin_amdgcn_mfma_f32_16x16x32_bf16(afh[i], bfh[j], acc[i][j], 0, 0, 0);

    if (prec) {
      bf16x8 afl[4], bfl[4];
#pragma unroll
      for (int i = 0; i < 4; i++)
        afl[i] = *(const bf16x8*)(Asl + (wr + i * 16 + l15) * 32 + lq * 8);
#pragma unroll
      for (int j = 0; j < 4; j++)
        bfl[j] = *(const bf16x8*)(Bsl + (wc + j * 16 + l15) * 32 + lq * 8);
#pragma unroll
      for (int i = 0; i < 4; i++)
#pragma unroll
        for (int j = 0; j < 4; j++) {
          acc[i][j] = __builtin_amdgcn_mfma_f32_16x16x32_bf16(afh[i], bfl[j], acc[i][j], 0, 0, 0);
          acc[i][j] = __builtin_amdgcn_mfma_f32_16x16x32_bf16(afl[i], bfh[j], acc[i][j], 0, 0, 0);
        }
    }
  }

#pragma unroll
  for (int j = 0; j < 4; j++) {
    const int col = Nb + wc + j * 16 + l15;
    const float bias = bqkv[col];
#pragma unroll
    for (int i = 0; i < 4; i++) {
#pragma unroll
      for (int r = 0; r < 4; r++) {
        const int row = Mb + wr + i * 16 + lq * 4 + r;
        const float xv = acc[i][j][r] + bias;
        const short hh = f2bf(xv);
        qh[(size_t)row * K3 + col] = hh;
        if (prec) ql[(size_t)row * K3 + col] = f2bf(xv - bf2f(hh));
      }
    }
  }
}

// ---------------------------------------------------------------------------
// Kernel 2: MFMA flash attention, 128-row q-tiles, 8 waves. Double-buffered
// K/V staging: iter issues tile t+1's K glds + V reg-load into buf^1, then
// computes tile t -> memory latency hidden under compute. ONE barrier/iter
// (the P-visibility barrier is removed: Ps[wv] is same-wave write/read).
// Numerics bit-identical to previous version (same op order).
// ---------------------------------------------------------------------------
__global__ __launch_bounds__(512) void attn_fwd(
    const short* __restrict__ qkvh,         // (8192, 3072) bf16 hi
    const short* __restrict__ qkvl,         // (8192, 3072) bf16 lo (q,k cols)
    __hip_bfloat16* __restrict__ attno)     // (8192, 1024) bf16
{
  __shared__ short Kh[2][4096], Kl[2][4096], Vt[2][4096];  // 48 KB
  __shared__ short Ps[8][1024];                            // 16 KB

  const int bx = blockIdx.x;
  const int qt = 15 - (bx & 15);            // heavy q-tiles dispatch first
  const int h  = (bx >> 4) & 15;
  const int b  = bx >> 8;
  const int qb = qt * 128;

  const int t    = threadIdx.x;
  const int lane = t & 63;
  const int wv   = t >> 6;                  // 0..7
  const int l15  = lane & 15;
  const int quad = lane >> 4;
  const size_t rowBase = (size_t)b * SEQ;

  // Q A-fragments: rows qb + 16*wv + l15 (load once)
  bf16x8 qah[2], qal[2];
  {
    const size_t qoff = (rowBase + qb + 16 * wv + l15) * K3 + h * DH;
#pragma unroll
    for (int ks = 0; ks < 2; ++ks) {
      qah[ks] = *(const bf16x8*)(qkvh + qoff + ks * 32 + quad * 8);
      qal[ks] = *(const bf16x8*)(qkvl + qoff + ks * 32 + quad * 8);
    }
  }

  float m_i[4], l_i[4];
  f32x4 O[4];
#pragma unroll
  for (int r = 0; r < 4; ++r) { m_i[r] = -1e30f; l_i[r] = 0.f; }
#pragma unroll
  for (int jd = 0; jd < 4; ++jd) O[jd] = (f32x4){0.f, 0.f, 0.f, 0.f};

  // K staging: waves 0-3 hi plane, 4-7 lo plane; 2 glds16 each.
  const short* gkbase = ((wv < 4) ? qkvh : qkvl) + DIM + h * DH;
  const int kw = wv & 3;
  // V staging: 512 threads x 8 shorts = 64x64 tile, one reg load each.
  const int vkey = t >> 3;
  const int vdb  = (t & 7) * 8;

  const int nkt = 2 * qt + 2;               // causal: keys <= qb+127
  bf16x8 vreg;

  // ---- prologue: stage tile 0 into buf 0 ----
  {
    const short* gk = gkbase + rowBase * K3;
    short* Kdst = (wv < 4) ? &Kh[0][0] : &Kl[0][0];
#pragma unroll
    for (int it = 0; it < 2; ++it) {
      const int row = kw * 16 + it * 8 + (lane >> 3);
      const int blk = ((lane & 7) ^ row) & 7;
      glds16(gk + (size_t)row * K3 + blk * 8, Kdst + (kw * 16 + it * 8) * 64);
    }
    vreg = *(const bf16x8*)(qkvh + (rowBase + vkey) * K3 + 2 * DIM + h * DH + vdb);
#pragma unroll
    for (int e = 0; e < 8; ++e) Vt[0][sw(vdb + e, vkey)] = vreg[e];
    asm volatile("s_waitcnt vmcnt(0)" ::: "memory");
  }
  __syncthreads();

  for (int kt = 0; kt < nkt; ++kt) {
    const int kb = kt * 64;
    const int cb = kt & 1;
    const bool more = (kt + 1 < nkt);

    // ---- issue next tile's staging (into buf cb^1) before computing ----
    if (more) {
      const short* gk = gkbase + (rowBase + kb + 64) * K3;
      short* Kdst = (wv < 4) ? &Kh[cb ^ 1][0] : &Kl[cb ^ 1][0];
#pragma unroll
      for (int it = 0; it < 2; ++it) {
        const int row = kw * 16 + it * 8 + (lane >> 3);
        const int blk = ((lane & 7) ^ row) & 7;
        glds16(gk + (size_t)row * K3 + blk * 8, Kdst + (kw * 16 + it * 8) * 64);
      }
      vreg = *(const bf16x8*)(qkvh + (rowBase + kb + 64 + vkey) * K3 +
                              2 * DIM + h * DH + vdb);
    }

    // wave-uniform: does this wave's row range see any of these keys?
    const bool active = (kb <= qb + 16 * wv + 15);

    if (active) {
      // ---- S = Q K^T, 4 n-tiles of 16 keys, split-bf16 (hh + hl + lh) ----
      f32x4 s[4];
#pragma unroll
      for (int j = 0; j < 4; ++j) s[j] = (f32x4){0.f, 0.f, 0.f, 0.f};
#pragma unroll
      for (int j = 0; j < 4; ++j) {
#pragma unroll
        for (int ks = 0; ks < 2; ++ks) {
          const bf16x8 kh = *(const bf16x8*)(&Kh[cb][sw(16 * j + l15, ks * 32 + quad * 8)]);
          const bf16x8 kl = *(const bf16x8*)(&Kl[cb][sw(16 * j + l15, ks * 32 + quad * 8)]);
          s[j] = __builtin_amdgcn_mfma_f32_16x16x32_bf16(qah[ks], kh, s[j], 0, 0, 0);
          s[j] = __builtin_amdgcn_mfma_f32_16x16x32_bf16(qal[ks], kh, s[j], 0, 0, 0);
          s[j] = __builtin_amdgcn_mfma_f32_16x16x32_bf16(qah[ks], kl, s[j], 0, 0, 0);
        }
      }

      // ---- scale, causal mask, online softmax (C-layout registers) ----
      const int qrow0 = qb + 16 * wv + 4 * quad;
      float p[4][4];
      float mt[4] = {-1e30f, -1e30f, -1e30f, -1e30f};
#pragma unroll
      for (int j = 0; j < 4; ++j) {
        const int key = kb + 16 * j + l15;
#pragma unroll
        for (int r = 0; r < 4; ++r) {
          float sv = s[j][r] * SCALE;
          if (key > qrow0 + r) sv = NEGV;
          p[j][r] = sv;
          mt[r] = fmaxf(mt[r], sv);
        }
      }
#pragma unroll
      for (int r = 0; r < 4; ++r) {
        mt[r] = fmaxf(mt[r], __shfl_xor(mt[r], 1));
        mt[r] = fmaxf(mt[r], __shfl_xor(mt[r], 2));
        mt[r] = fmaxf(mt[r], __shfl_xor(mt[r], 4));
        mt[r] = fmaxf(mt[r], __shfl_xor(mt[r], 8));
      }
      float alpha[4];
#pragma unroll
      for (int r = 0; r < 4; ++r) {
        const float mn = fmaxf(m_i[r], mt[r]);
        alpha[r] = __expf(m_i[r] - mn);
        m_i[r] = mn;
      }
      float ls[4] = {0.f, 0.f, 0.f, 0.f};
#pragma unroll
      for (int j = 0; j < 4; ++j)
#pragma unroll
        for (int r = 0; r < 4; ++r) {
          p[j][r] = __expf(p[j][r] - m_i[r]);
          ls[r] += p[j][r];
        }
#pragma unroll
      for (int r = 0; r < 4; ++r) {
        ls[r] += __shfl_xor(ls[r], 1);
        ls[r] += __shfl_xor(ls[r], 2);
        ls[r] += __shfl_xor(ls[r], 4);
        ls[r] += __shfl_xor(ls[r], 8);
        l_i[r] = l_i[r] * alpha[r] + ls[r];
      }
#pragma unroll
      for (int jd = 0; jd < 4; ++jd)
#pragma unroll
        for (int r = 0; r < 4; ++r) O[jd][r] *= alpha[r];

      // ---- P (C-layout) -> per-wave LDS; same-wave reload (no barrier) ----
#pragma unroll
      for (int j = 0; j < 4; ++j)
#pragma unroll
        for (int r = 0; r < 4; ++r)
          Ps[wv][sw(4 * quad + r, 16 * j + l15)] = f2bf(p[j][r]);

      // ---- O += P V : A = P (A-layout reload), B = Vt (transposed V) ----
#pragma unroll
      for (int ks = 0; ks < 2; ++ks) {
        const bf16x8 pa = *(const bf16x8*)(&Ps[wv][sw(l15, ks * 32 + quad * 8)]);
#pragma unroll
        for (int jd = 0; jd < 4; ++jd) {
          const bf16x8 vb = *(const bf16x8*)(&Vt[cb][sw(16 * jd + l15, ks * 32 + quad * 8)]);
          O[jd] = __builtin_amdgcn_mfma_f32_16x16x32_bf16(pa, vb, O[jd], 0, 0, 0);
        }
      }
    }

    // ---- finish staging: V scatter into buf cb^1, then single barrier ----
    if (more) {
      asm volatile("s_waitcnt vmcnt(0)" ::: "memory");  // vreg + K glds landed
#pragma unroll
      for (int e = 0; e < 8; ++e) Vt[cb ^ 1][sw(vdb + e, vkey)] = vreg[e];
    }
    __syncthreads();
  }

  // epilogue: O/l -> bf16 attn ws (C-layout scatter, once per block)
#pragma unroll
  for (int jd = 0; jd < 4; ++jd) {
#pragma unroll
    for (int r = 0; r < 4; ++r) {
      const int row = qb + 16 * wv + 4 * quad + r;
      attno[(rowBase + row) * DIM + h * DH + 16 * jd + l15] =
          __float2bfloat16(O[jd][r] / l_i[r]);
    }
  }
}

// ---------------------------------------------------------------------------
// Kernel 3a: out = attn @ w_out^T + b_out, both operands pre-bf16, glds
// staging (R1 qkv_gemm_pre structure, no in-loop conversion).
// ---------------------------------------------------------------------------
__global__ __launch_bounds__(256) void out_gemm_pre(
    const short* __restrict__ a,             // (8192, 1024) attn bf16
    const short* __restrict__ wob,           // (1024, 1024) bf16
    const float* __restrict__ bo,            // (1024) fp32
    float* __restrict__ out)                 // (8192, 1024) fp32
{
  __shared__ short As[128 * 32];
  __shared__ short Bs[128 * 32];

  const int t    = threadIdx.x;
  const int lane = t & 63;
  const int wv   = t >> 6;
  const int Mb   = blockIdx.y * 128;
  const int Nb   = blockIdx.x * 128;
  const int wr   = (wv >> 1) * 64;
  const int wc   = (wv & 1) * 64;
  const int l15  = lane & 15;
  const int lq   = lane >> 4;
  const int grow = lane >> 2;
  const int gcol = (lane & 3) * 8;

  f32x4 acc[4][4];
#pragma unroll
  for (int i = 0; i < 4; i++)
#pragma unroll
    for (int j = 0; j < 4; j++) acc[i][j] = (f32x4){0.f, 0.f, 0.f, 0.f};

  for (int k0 = 0; k0 < DIM; k0 += 32) {
    __syncthreads();
#pragma unroll
    for (int it = 0; it < 2; ++it) {
      const int r0 = wv * 32 + it * 16;
      glds16(a   + (size_t)(Mb + r0 + grow) * DIM + k0 + gcol, As + r0 * 32);
      glds16(wob + (size_t)(Nb + r0 + grow) * DIM + k0 + gcol, Bs + r0 * 32);
    }
    __syncthreads();

    bf16x8 af[4], bfr[4];
#pragma unroll
    for (int i = 0; i < 4; i++)
      af[i] = *(const bf16x8*)(As + (wr + i * 16 + l15) * 32 + lq * 8);
#pragma unroll
    for (int j = 0; j < 4; j++)
      bfr[j] = *(const bf16x8*)(Bs + (wc + j * 16 + l15) * 32 + lq * 8);
#pragma unroll
    for (int i = 0; i < 4; i++)
#pragma unroll
      for (int j = 0; j < 4; j++)
        acc[i][j] = __builtin_amdgcn_mfma_f32_16x16x32_bf16(af[i], bfr[j], acc[i][j], 0, 0, 0);
  }

#pragma unroll
  for (int j = 0; j < 4; j++) {
    const int col = Nb + wc + j * 16 + l15;
    const float bias = bo[col];
#pragma unroll
    for (int i = 0; i < 4; i++) {
#pragma unroll
      for (int r = 0; r < 4; r++) {
        const int row = Mb + wr + i * 16 + lq * 4 + r;
        out[(size_t)row * DIM + col] = acc[i][j][r] + bias;
      }
    }
  }
}

// ---------------------------------------------------------------------------
// Kernel 3b (fallback): out = attn @ w_out^T + b_out, fp32 W in-loop cvt.
// ---------------------------------------------------------------------------
__global__ __launch_bounds__(256) void out_gemm(
    const __hip_bfloat16* __restrict__ a,    // (8192, 1024) attn, bf16
    const float* __restrict__ wo,            // (1024, 1024) fp32
    const float* __restrict__ bo,            // (1024) fp32
    float* __restrict__ out)                 // (8192, 1024) fp32
{
  __shared__ short As[128 * 32];
  __shared__ short Bs[128 * 32];

  const int t    = threadIdx.x;
  const int lane = t & 63;
  const int wv   = t >> 6;
  const int Mb   = blockIdx.y * 128;
  const int Nb   = blockIdx.x * 128;
  const int wr   = (wv >> 1) * 64;
  const int wc   = (wv & 1) * 64;
  const int l15  = lane & 15;
  const int lq   = lane >> 4;
  const int srow = wv * 16 + (lane >> 2);
  const int scol = (lane & 3) * 8;

  f32x4 acc[4][4];
#pragma unroll
  for (int i = 0; i < 4; i++)
#pragma unroll
    for (int j = 0; j < 4; j++) acc[i][j] = (f32x4){0.f, 0.f, 0.f, 0.f};

  for (int k0 = 0; k0 < DIM; k0 += 32) {
    bf16x8 areg[2], breg[2];
#pragma unroll
    for (int it = 0; it < 2; ++it) {
      areg[it] = *(const bf16x8*)(a + (size_t)(Mb + it * 64 + srow) * DIM + k0 + scol);
      const float* bp = wo + (size_t)(Nb + it * 64 + srow) * DIM + k0 + scol;
      const float4 b0 = *(const float4*)(bp);
      const float4 b1 = *(const float4*)(bp + 4);
      const float bf8[8] = {b0.x, b0.y, b0.z, b0.w, b1.x, b1.y, b1.z, b1.w};
#pragma unroll
      for (int e = 0; e < 8; e++) breg[it][e] = f2bf(bf8[e]);
    }
    __syncthreads();
#pragma unroll
    for (int it = 0; it < 2; ++it) {
      *(bf16x8*)(As + (it * 64 + srow) * 32 + scol) = areg[it];
      *(bf16x8*)(Bs + (it * 64 + srow) * 32 + scol) = breg[it];
    }
    __syncthreads();

    bf16x8 af[4], bfr[4];
#pragma unroll
    for (int i = 0; i < 4; i++)
      af[i] = *(const bf16x8*)(As + (wr + i * 16 + l15) * 32 + lq * 8);
#pragma unroll
    for (int j = 0; j < 4; j++)
      bfr[j] = *(const bf16x8*)(Bs + (wc + j * 16 + l15) * 32 + lq * 8);
#pragma unroll
    for (int i = 0; i < 4; i++)
#pragma unroll
      for (int j = 0; j < 4; j++)
        acc[i][j] = __builtin_amdgcn_mfma_f32_16x16x32_bf16(af[i], bfr[j], acc[i][j], 0, 0, 0);
  }

#pragma unroll
  for (int j = 0; j < 4; j++) {
    const int col = Nb + wc + j * 16 + l15;
    const float bias = bo[col];
#pragma unroll
    for (int i = 0; i < 4; i++) {
#pragma unroll
      for (int r = 0; r < 4; r++) {
        const int row = Mb + wr + i * 16 + lq * 4 + r;
        out[(size_t)row * DIM + col] = acc[i][j][r] + bias;
      }
    }
  }
}

// ---------------------------------------------------------------------------
extern "C" void kernel_launch(void* const* d_in, const int* in_sizes, int n_in,
                              void* d_out, int out_size, void* d_ws, size_t ws_size,
                              hipStream_t stream) {
  const float* q    = (const float*)d_in[0];
  const float* k    = (const float*)d_in[1];
  const float* v    = (const float*)d_in[2];
  const float* wqkv = (const float*)d_in[3];
  const float* bqkv = (const float*)d_in[4];
  const float* wout = (const float*)d_in[5];
  const float* bout = (const float*)d_in[6];

  // ws layout:
  //   [0,48MB)    qkv_hi bf16 (8192x3072)
  //   [48,96MB)   qkv_lo bf16 (8192x3072; only q,k cols written/read)
  //   [96MB,...)  prep path: A_hi(48) A_lo(48) B_hi(18) B_lo(18) = +132MB
  //               attn bf16 (16MB) aliases A_hi[0:16MB] (A region dead after
  //               qkv_gemm_8p); wout bf16 (2MB) aliases A_hi[16:18MB].
  //   fallback:   attn bf16 at 96MB (112MB total)
  const size_t PLANE = (size_t)MROWS * K3 * 2;        // 50331648 B
  const size_t BPLN  = (size_t)K3 * K3 * 2;           // 18874368 B
  short* qh = (short*)d_ws;
  short* ql = (short*)((char*)d_ws + PLANE);
  char*  p2 = (char*)d_ws + 2 * PLANE;                // offset 96 MB
  __hip_bfloat16* attnws = (__hip_bfloat16*)p2;

  const size_t NEED = 2 * PLANE + 2 * PLANE + 2 * BPLN;  // 228 MB

  if (ws_size >= NEED) {
    short* Ah = (short*)p2;
    short* Al = Ah + (size_t)MROWS * K3;
    short* Bh = Al + (size_t)MROWS * K3;
    short* Bl = Bh + (size_t)K3 * K3;
    short* wob = (short*)(p2 + (size_t)MROWS * DIM * 2);  // after attnws
    prep_x<<<4096, 256, 0, stream>>>(q, k, v, Ah, Al);
    prep_w<<<2048, 256, 0, stream>>>(wqkv, Bh, Bl);
    qkv_gemm_8p<<<dim3(256), 512, 0, stream>>>(Ah, Al, Bh, Bl, bqkv, qh, ql);
    prep_wo<<<256, 256, 0, stream>>>(wout, wob);          // A region now dead
    attn_fwd<<<dim3(4 * HEADS * (SEQ / 128)), 512, 0, stream>>>(qh, ql, attnws);
    out_gemm_pre<<<dim3(DIM / 128, MROWS / 128), 256, 0, stream>>>(
        (const short*)attnws, wob, bout, (float*)d_out);
  } else {
    qkv_gemm_fly<<<dim3(K3 / 128, MROWS / 128), 256, 0, stream>>>(
        q, k, v, wqkv, bqkv, qh, ql);
    attn_fwd<<<dim3(4 * HEADS * (SEQ / 128)), 512, 0, stream>>>(qh, ql, attnws);
    out_gemm<<<dim3(DIM / 128, MROWS / 128), 256, 0, stream>>>(attnws, wout, bout,
                                                               (float*)d_out);
  }
}

// Round 5
// 770.990 us; speedup vs baseline: 1.0640x; 1.0640x over previous
//
#include <hip/hip_runtime.h>
#include <hip/hip_bf16.h>

// Problem constants: B=4, N=2048, D=1024, H=16, dh=64. All I/O fp32.
#define SEQ   2048
#define DIM   1024
#define HEADS 16
#define DH    64
#define MROWS 8192            // B*N
#define K3    3072            // 3*D
#define NEGV  (-32767.0f)     // -2^15+1, matches reference mask constant
#define SCALE 8.0f            // sqrt(dh) — reference MULTIPLIES by sqrt(d)

typedef __attribute__((ext_vector_type(8))) short bf16x8;
typedef __attribute__((ext_vector_type(4))) float f32x4;

// bf16 round-to-nearest-even via bit ops (finite inputs only)
__device__ __forceinline__ short f2bf(float x) {
  union { float f; unsigned u; } v; v.f = x;
  unsigned r = v.u + 0x7FFF + ((v.u >> 16) & 1);
  return (short)(r >> 16);
}
__device__ __forceinline__ float bf2f(short s) {
  union { float f; unsigned u; } v; v.u = ((unsigned)(unsigned short)s) << 16;
  return v.f;
}
__device__ __forceinline__ void split1(float x, short& h, short& l) {
  h = f2bf(x);
  l = f2bf(x - bf2f(h));
}
__device__ __forceinline__ void cvt_split8(const float4 a, const float4 b,
                                           bf16x8& hi, bf16x8& lo) {
  const float f[8] = {a.x, a.y, a.z, a.w, b.x, b.y, b.z, b.w};
#pragma unroll
  for (int i = 0; i < 8; i++) {
    short h, l; split1(f[i], h, l);
    hi[i] = h; lo[i] = l;
  }
}

// async global->LDS, 16B per lane. LDS dest is wave-uniform base; HW writes
// lane l at base + l*16 bytes. Global src is per-lane.
__device__ __forceinline__ void glds16(const void* g, void* l) {
  __builtin_amdgcn_global_load_lds(
      (const __attribute__((address_space(1))) void*)g,
      (__attribute__((address_space(3))) void*)l, 16, 0, 0);
}

// XOR-swizzled LDS index (shorts) for 64-col row-major tiles: 8-short (16B)
// blocks permuted by row&7 -> ds_read_b128-able fragments, spread banks.
__device__ __forceinline__ int sw(int row, int col) {
  return row * 64 + ((((col >> 3) ^ row) & 7) << 3) + (col & 7);
}

// ---------------------------------------------------------------------------
// Prep kernels: one-time fp32 -> bf16 (hi/lo RNE split where needed).
// ---------------------------------------------------------------------------
__global__ __launch_bounds__(256) void prep_x(
    const float* __restrict__ q, const float* __restrict__ k,
    const float* __restrict__ v,
    short* __restrict__ ah, short* __restrict__ al)  // (8192, 3072) bf16 each
{
  const int n = MROWS * (K3 / 4);                    // float4 work items
  for (int i = blockIdx.x * 256 + threadIdx.x; i < n; i += gridDim.x * 256) {
    const int r  = i / 768;                          // 3072/4 cols per row
    const int c4 = i - r * 768;
    const float* src = (c4 < 256) ? q : ((c4 < 512) ? k : v);
    const int cc = c4 & 255;
    const float4 f = *(const float4*)(src + ((size_t)r * 256 + cc) * 4);
    const float fa[4] = {f.x, f.y, f.z, f.w};
    short hi[4], lo[4];
#pragma unroll
    for (int e = 0; e < 4; ++e) split1(fa[e], hi[e], lo[e]);
    const size_t o = (size_t)r * K3 + c4 * 4;
    *(short4*)(ah + o) = make_short4(hi[0], hi[1], hi[2], hi[3]);
    *(short4*)(al + o) = make_short4(lo[0], lo[1], lo[2], lo[3]);
  }
}

__global__ __launch_bounds__(256) void prep_w(
    const float* __restrict__ w,                     // (3072,3072) fp32
    short* __restrict__ bh, short* __restrict__ bl)  // bf16 each
{
  const int n = (K3 * K3) / 4;
  for (int i = blockIdx.x * 256 + threadIdx.x; i < n; i += gridDim.x * 256) {
    const float4 f = ((const float4*)w)[i];
    const float fa[4] = {f.x, f.y, f.z, f.w};
    short hi[4], lo[4];
#pragma unroll
    for (int e = 0; e < 4; ++e) split1(fa[e], hi[e], lo[e]);
    ((short4*)bh)[i] = make_short4(hi[0], hi[1], hi[2], hi[3]);
    ((short4*)bl)[i] = make_short4(lo[0], lo[1], lo[2], lo[3]);
  }
}

__global__ __launch_bounds__(256) void prep_wo(
    const float* __restrict__ w,                     // (1024,1024) fp32
    short* __restrict__ wb)                          // bf16
{
  const int n = (DIM * DIM) / 4;
  for (int i = blockIdx.x * 256 + threadIdx.x; i < n; i += gridDim.x * 256) {
    const float4 f = ((const float4*)w)[i];
    ((short4*)wb)[i] = make_short4(f2bf(f.x), f2bf(f.y), f2bf(f.z), f2bf(f.w));
  }
}

// ---------------------------------------------------------------------------
// Kernel 1a: qkv GEMM, 256x256 tiles, 8-phase counted-vmcnt schedule.
// Grid = 256 blocks; each block computes ONE heavy (q,k cols; packed-K 144
// tiles) 256x256 tile, then HALF of one light (v cols; 48 tiles) 256-wide
// tile (128 rows) -> uniform 168 tile-equivalents per block (load-balanced).
// ---------------------------------------------------------------------------
__device__ __forceinline__ void stage_half(const short* __restrict__ src,
                                           short* dst, int wv, int lane) {
  // half-tile = 128 rows x 64 cols bf16 = 16KB; wave wv covers 2x1KB pieces.
  // LDS dest linear; source col-block pre-swizzled (involution cb^row&7).
#pragma unroll
  for (int e = 0; e < 2; ++e) {
    const int idx = (wv * 2 + e) * 512 + lane * 8;   // linear short index
    const int row = idx >> 6;
    const int cb  = (idx >> 3) & 7;
    const int cbs = (cb ^ row) & 7;
    glds16(src + (size_t)row * K3 + cbs * 8, dst + (wv * 2 + e) * 512);
  }
}

__global__ __launch_bounds__(512, 2) void qkv_gemm_8p(
    const short* __restrict__ Ah, const short* __restrict__ Al,
    const short* __restrict__ Bh, const short* __restrict__ Bl,
    const float* __restrict__ bqkv,
    short* __restrict__ qh, short* __restrict__ ql)
{
  __shared__ short L[2][4][8192];   // [buf][A0,A1,B0,B1][128*64], 128 KB

  const int t    = threadIdx.x;
  const int lane = t & 63;
  const int wv   = t >> 6;          // 0..7
  const int wr   = wv >> 2;         // 0..1  (M half)
  const int wc   = wv & 3;          // 0..3  (N slice)
  const int l15  = lane & 15;
  const int lq   = lane >> 4;

  // ======================= HEAVY: q,k columns =======================
  // XCD-chunked bijective swizzle over 256 heavy tiles (32 M x 8 N).
  const int w  = (blockIdx.x & 7) * 32 + (blockIdx.x >> 3);
  const int Mb = (w & 31) * 256;
  const int Nb = (w >> 5) * 256;    // 0..1792 (q,k cols)
  const int nt = 144;               // packed-K

  // tile kt -> source for half h (0,1 = A halves; 2,3 = B halves)
  auto tsrc = [&](int kt, int h) -> const short* {
    kt = (kt < nt - 1) ? kt : (nt - 1);
    const int seg = (kt >= 96) ? 2 : ((kt >= 48) ? 1 : 0);
    const int k0  = (kt - seg * 48) * 64;
    if (h < 2) {
      const short* Apl = (seg == 2) ? Al : Ah;
      return Apl + (size_t)(Mb + h * 128) * K3 + k0;
    }
    const short* Bpl = (seg == 1) ? Bl : Bh;
    return Bpl + (size_t)(Nb + (h - 2) * 128) * K3 + k0;
  };

  f32x4 acc[8][4];
#pragma unroll
  for (int i = 0; i < 8; i++)
#pragma unroll
    for (int j = 0; j < 4; j++) acc[i][j] = (f32x4){0.f, 0.f, 0.f, 0.f};

  // prologue: tile 0 -> buf0 (all 4 halves), tile 1 -> buf1 B halves
  stage_half(tsrc(0, 0), &L[0][0][0], wv, lane);
  stage_half(tsrc(0, 1), &L[0][1][0], wv, lane);
  stage_half(tsrc(0, 2), &L[0][2][0], wv, lane);
  stage_half(tsrc(0, 3), &L[0][3][0], wv, lane);
  stage_half(tsrc(1, 2), &L[1][2][0], wv, lane);
  stage_half(tsrc(1, 3), &L[1][3][0], wv, lane);
  asm volatile("s_waitcnt vmcnt(4)" ::: "memory");   // buf0 landed
  __builtin_amdgcn_s_barrier();

  bf16x8 bfr[4][2];                 // B frags, live across each 4-phase group

  for (int kp = 0; kp < nt; kp += 2) {
#pragma unroll
    for (int p = 0; p < 8; ++p) {
      const int buf = p >> 2;
      const int qtr = p & 3;
      const int mi0 = qtr * 2;

      if (qtr == 0) {
#pragma unroll
        for (int ni = 0; ni < 4; ++ni)
#pragma unroll
          for (int ks = 0; ks < 2; ++ks)
            bfr[ni][ks] = *(const bf16x8*)(
                &L[buf][2 + (wc >> 1)][sw((wc & 1) * 64 + ni * 16 + l15,
                                          ks * 32 + lq * 8)]);
      }
      bf16x8 afr[2][2];
#pragma unroll
      for (int m = 0; m < 2; ++m)
#pragma unroll
        for (int ks = 0; ks < 2; ++ks)
          afr[m][ks] = *(const bf16x8*)(
              &L[buf][wr][sw((mi0 + m) * 16 + l15, ks * 32 + lq * 8)]);

      {
        const int SB[8] = {1, 1, 0, 0, 0, 0, 1, 1};
        const int SH[8] = {0, 1, 2, 3, 0, 1, 2, 3};
        const int SD[8] = {1, 1, 2, 2, 2, 2, 3, 3};
        stage_half(tsrc(kp + SD[p], SH[p]), &L[SB[p]][SH[p]][0], wv, lane);
      }

      if (qtr == 3) asm volatile("s_waitcnt vmcnt(4)" ::: "memory");
      __builtin_amdgcn_s_barrier();
      asm volatile("s_waitcnt lgkmcnt(0)" ::: "memory");
      __builtin_amdgcn_sched_barrier(0);

      __builtin_amdgcn_s_setprio(1);
#pragma unroll
      for (int m = 0; m < 2; ++m)
#pragma unroll
        for (int ni = 0; ni < 4; ++ni)
#pragma unroll
          for (int ks = 0; ks < 2; ++ks)
            acc[mi0 + m][ni] = __builtin_amdgcn_mfma_f32_16x16x32_bf16(
                afr[m][ks], bfr[ni][ks], acc[mi0 + m][ni], 0, 0, 0);
      __builtin_amdgcn_s_setprio(0);
      __builtin_amdgcn_s_barrier();
    }
  }

  // heavy epilogue: bias + bf16 hi/lo split output
#pragma unroll
  for (int ni = 0; ni < 4; ++ni) {
    const int col = Nb + wc * 64 + ni * 16 + l15;
    const float bias = bqkv[col];
#pragma unroll
    for (int mi = 0; mi < 8; ++mi) {
#pragma unroll
      for (int r = 0; r < 4; ++r) {
        const int row = Mb + wr * 128 + mi * 16 + lq * 4 + r;
        const float xv = acc[mi][ni][r] + bias;
        const short hh = f2bf(xv);
        qh[(size_t)row * K3 + col] = hh;
        ql[(size_t)row * K3 + col] = f2bf(xv - bf2f(hh));
      }
    }
  }

  // ======================= LIGHT: v columns (half tile) =======================
  asm volatile("s_waitcnt vmcnt(0)" ::: "memory");
  __builtin_amdgcn_s_barrier();

  const int lt  = blockIdx.x >> 1;                   // 0..127 light tiles
  const int MbL = (lt & 31) * 256 + (blockIdx.x & 1) * 128;
  const int NbL = 2 * DIM + (lt >> 5) * 256;

  auto tsrcL = [&](int kt, int h) -> const short* {
    kt = (kt < 47) ? kt : 47;
    const int k0 = kt * 64;
    if (h == 0) return Ah + (size_t)MbL * K3 + k0;
    return Bh + (size_t)(NbL + (h - 2) * 128) * K3 + k0;
  };

#pragma unroll
  for (int i = 0; i < 4; i++)
#pragma unroll
    for (int j = 0; j < 4; j++) acc[i][j] = (f32x4){0.f, 0.f, 0.f, 0.f};

  stage_half(tsrcL(0, 0), &L[0][0][0], wv, lane);
  stage_half(tsrcL(0, 2), &L[0][2][0], wv, lane);
  stage_half(tsrcL(0, 3), &L[0][3][0], wv, lane);
  stage_half(tsrcL(1, 2), &L[1][2][0], wv, lane);
  stage_half(tsrcL(1, 3), &L[1][3][0], wv, lane);
  asm volatile("s_waitcnt vmcnt(4)" ::: "memory");
  __builtin_amdgcn_s_barrier();

  for (int kp = 0; kp < 48; kp += 2) {
#pragma unroll
    for (int p = 0; p < 4; ++p) {
      const int buf = p >> 1;
      const int mh  = p & 1;

      if (mh == 0) {
#pragma unroll
        for (int ni = 0; ni < 4; ++ni)
#pragma unroll
          for (int ks = 0; ks < 2; ++ks)
            bfr[ni][ks] = *(const bf16x8*)(
                &L[buf][2 + (wc >> 1)][sw((wc & 1) * 64 + ni * 16 + l15,
                                          ks * 32 + lq * 8)]);
      }
      bf16x8 afr[2][2];
#pragma unroll
      for (int m = 0; m < 2; ++m)
#pragma unroll
        for (int ks = 0; ks < 2; ++ks)
          afr[m][ks] = *(const bf16x8*)(
              &L[buf][0][sw(wr * 64 + (mh * 2 + m) * 16 + l15,
                            ks * 32 + lq * 8)]);

      if (p == 0) {
        stage_half(tsrcL(kp + 1, 0), &L[1][0][0], wv, lane);
      } else if (p == 1) {
        stage_half(tsrcL(kp + 2, 2), &L[0][2][0], wv, lane);
        stage_half(tsrcL(kp + 2, 3), &L[0][3][0], wv, lane);
      } else if (p == 2) {
        stage_half(tsrcL(kp + 2, 0), &L[0][0][0], wv, lane);
      } else {
        stage_half(tsrcL(kp + 3, 2), &L[1][2][0], wv, lane);
        stage_half(tsrcL(kp + 3, 3), &L[1][3][0], wv, lane);
      }

      if (mh == 1) asm volatile("s_waitcnt vmcnt(4)" ::: "memory");
      __builtin_amdgcn_s_barrier();
      asm volatile("s_waitcnt lgkmcnt(0)" ::: "memory");
      __builtin_amdgcn_sched_barrier(0);

      __builtin_amdgcn_s_setprio(1);
#pragma unroll
      for (int m = 0; m < 2; ++m)
#pragma unroll
        for (int ni = 0; ni < 4; ++ni)
#pragma unroll
          for (int ks = 0; ks < 2; ++ks)
            acc[mh * 2 + m][ni] = __builtin_amdgcn_mfma_f32_16x16x32_bf16(
                afr[m][ks], bfr[ni][ks], acc[mh * 2 + m][ni], 0, 0, 0);
      __builtin_amdgcn_s_setprio(0);
      __builtin_amdgcn_s_barrier();
    }
  }

#pragma unroll
  for (int ni = 0; ni < 4; ++ni) {
    const int col = NbL + wc * 64 + ni * 16 + l15;
    const float bias = bqkv[col];
#pragma unroll
    for (int mi = 0; mi < 4; ++mi) {
#pragma unroll
      for (int r = 0; r < 4; ++r) {
        const int row = MbL + wr * 64 + mi * 16 + lq * 4 + r;
        qh[(size_t)row * K3 + col] = f2bf(acc[mi][ni][r] + bias);
      }
    }
  }
}

// ---------------------------------------------------------------------------
// Kernel 1b (fallback, ws too small for prep): in-loop cvt, hi/lo output.
// ---------------------------------------------------------------------------
__global__ __launch_bounds__(256) void qkv_gemm_fly(
    const float* __restrict__ q,
    const float* __restrict__ k,
    const float* __restrict__ v,
    const float* __restrict__ wqkv,
    const float* __restrict__ bqkv,
    short* __restrict__ qh, short* __restrict__ ql)
{
  __shared__ short Ash[128 * 32];
  __shared__ short Asl[128 * 32];
  __shared__ short Bsh[128 * 32];
  __shared__ short Bsl[128 * 32];

  const int t    = threadIdx.x;
  const int lane = t & 63;
  const int wv   = t >> 6;
  const int Mb   = blockIdx.y * 128;
  const int Nb   = blockIdx.x * 128;
  const bool prec = (Nb < 2 * DIM);
  const int wr   = (wv >> 1) * 64;
  const int wc   = (wv & 1) * 64;
  const int l15  = lane & 15;
  const int lq   = lane >> 4;
  const int srow = wv * 16 + (lane >> 2);
  const int scol = (lane & 3) * 8;

  f32x4 acc[4][4];
#pragma unroll
  for (int i = 0; i < 4; i++)
#pragma unroll
    for (int j = 0; j < 4; j++) acc[i][j] = (f32x4){0.f, 0.f, 0.f, 0.f};

  for (int k0 = 0; k0 < K3; k0 += 32) {
    const float* src = (k0 < DIM) ? q : ((k0 < 2 * DIM) ? k : v);
    const int koff = (k0 & (DIM - 1)) + scol;

    bf16x8 ah[2], al[2], bh[2], bl[2];
#pragma unroll
    for (int it = 0; it < 2; ++it) {
      const float* ap = src + (size_t)(Mb + it * 64 + srow) * DIM + koff;
      cvt_split8(*(const float4*)(ap), *(const float4*)(ap + 4), ah[it], al[it]);
      const float* bp = wqkv + (size_t)(Nb + it * 64 + srow) * K3 + k0 + scol;
      cvt_split8(*(const float4*)(bp), *(const float4*)(bp + 4), bh[it], bl[it]);
    }
    __syncthreads();
#pragma unroll
    for (int it = 0; it < 2; ++it) {
      *(bf16x8*)(Ash + (it * 64 + srow) * 32 + scol) = ah[it];
      *(bf16x8*)(Bsh + (it * 64 + srow) * 32 + scol) = bh[it];
      if (prec) {
        *(bf16x8*)(Asl + (it * 64 + srow) * 32 + scol) = al[it];
        *(bf16x8*)(Bsl + (it * 64 + srow) * 32 + scol) = bl[it];
      }
    }
    __syncthreads();

    bf16x8 afh[4], bfh[4];
#pragma unroll
    for (int i = 0; i < 4; i++)
      afh[i] = *(const bf16x8*)(Ash + (wr + i * 16 + l15) * 32 + lq * 8);
#pragma unroll
    for (int j = 0; j < 4; j++)
      bfh[j] = *(const bf16x8*)(Bsh + (wc + j * 16 + l15) * 32 + lq * 8);
#pragma unroll
    for (int i = 0; i < 4; i++)
#pragma unroll
      for (int j = 0; j < 4; j++)
        acc[i][j] = __builtin_amdgcn_mfma_f32_16x16x32_bf16(afh[i], bfh[j], acc[i][j], 0, 0, 0);

    if (prec) {
      bf16x8 afl[4], bfl[4];
#pragma unroll
      for (int i = 0; i < 4; i++)
        afl[i] = *(const bf16x8*)(Asl + (wr + i * 16 + l15) * 32 + lq * 8);
#pragma unroll
      for (int j = 0; j < 4; j++)
        bfl[j] = *(const bf16x8*)(Bsl + (wc + j * 16 + l15) * 32 + lq * 8);
#pragma unroll
      for (int i = 0; i < 4; i++)
#pragma unroll
        for (int j = 0; j < 4; j++) {
          acc[i][j] = __builtin_amdgcn_mfma_f32_16x16x32_bf16(afh[i], bfl[j], acc[i][j], 0, 0, 0);
          acc[i][j] = __builtin_amdgcn_mfma_f32_16x16x32_bf16(afl[i], bfh[j], acc[i][j], 0, 0, 0);
        }
    }
  }

#pragma unroll
  for (int j = 0; j < 4; j++) {
    const int col = Nb + wc + j * 16 + l15;
    const float bias = bqkv[col];
#pragma unroll
    for (int i = 0; i < 4; i++) {
#pragma unroll
      for (int r = 0; r < 4; r++) {
        const int row = Mb + wr + i * 16 + lq * 4 + r;
        const float xv = acc[i][j][r] + bias;
        const short hh = f2bf(xv);
        qh[(size_t)row * K3 + col] = hh;
        if (prec) ql[(size_t)row * K3 + col] = f2bf(xv - bf2f(hh));
      }
    }
  }
}

// ---------------------------------------------------------------------------
// Kernel 2: MFMA flash attention, 128-row q-tiles, 8 waves, double-buffered
// K/V staging (issue-early/write-late), ONE barrier/iter. This round:
//  - __launch_bounds__(512,4): cap VGPR<=128 -> guarantee 2 blocks/CU
//    (cross-block overlap hides the softmax VALU chain).
//  - Q pre-scaled by 8 (bit-exact pow2 shift) -> drop per-iter scale mul.
//  - causal mask only on diagonal iterations (wave-uniform branch).
//  - s_setprio around MFMA clusters (T5).
//  - P->LDS store fused into exp loop (shorter p[] liveness).
// Numerics bit-identical to previous version.
// ---------------------------------------------------------------------------
__global__ __launch_bounds__(512, 4) void attn_fwd(
    const short* __restrict__ qkvh,         // (8192, 3072) bf16 hi
    const short* __restrict__ qkvl,         // (8192, 3072) bf16 lo (q,k cols)
    __hip_bfloat16* __restrict__ attno)     // (8192, 1024) bf16
{
  __shared__ short Kh[2][4096], Kl[2][4096], Vt[2][4096];  // 48 KB
  __shared__ short Ps[8][1024];                            // 16 KB

  const int bx = blockIdx.x;
  const int qt = 15 - (bx & 15);            // heavy q-tiles dispatch first
  const int h  = (bx >> 4) & 15;
  const int b  = bx >> 8;
  const int qb = qt * 128;

  const int t    = threadIdx.x;
  const int lane = t & 63;
  const int wv   = t >> 6;                  // 0..7
  const int l15  = lane & 15;
  const int quad = lane >> 4;
  const size_t rowBase = (size_t)b * SEQ;

  // Q A-fragments: rows qb + 16*wv + l15 (load once), pre-scaled by 8
  // (exact: x8 is an exponent shift for every bf16 value incl. +-0).
  bf16x8 qah[2], qal[2];
  {
    const size_t qoff = (rowBase + qb + 16 * wv + l15) * K3 + h * DH;
#pragma unroll
    for (int ks = 0; ks < 2; ++ks) {
      qah[ks] = *(const bf16x8*)(qkvh + qoff + ks * 32 + quad * 8);
      qal[ks] = *(const bf16x8*)(qkvl + qoff + ks * 32 + quad * 8);
#pragma unroll
      for (int e = 0; e < 8; ++e) {
        qah[ks][e] = f2bf(SCALE * bf2f(qah[ks][e]));
        qal[ks][e] = f2bf(SCALE * bf2f(qal[ks][e]));
      }
    }
  }

  float m_i[4], l_i[4];
  f32x4 O[4];
#pragma unroll
  for (int r = 0; r < 4; ++r) { m_i[r] = -1e30f; l_i[r] = 0.f; }
#pragma unroll
  for (int jd = 0; jd < 4; ++jd) O[jd] = (f32x4){0.f, 0.f, 0.f, 0.f};

  // K staging: waves 0-3 hi plane, 4-7 lo plane; 2 glds16 each.
  const short* gkbase = ((wv < 4) ? qkvh : qkvl) + DIM + h * DH;
  const int kw = wv & 3;
  // V staging: 512 threads x 8 shorts = 64x64 tile, one reg load each.
  const int vkey = t >> 3;
  const int vdb  = (t & 7) * 8;

  const int nkt = 2 * qt + 2;               // causal: keys <= qb+127
  bf16x8 vreg;

  // ---- prologue: stage tile 0 into buf 0 ----
  {
    const short* gk = gkbase + rowBase * K3;
    short* Kdst = (wv < 4) ? &Kh[0][0] : &Kl[0][0];
#pragma unroll
    for (int it = 0; it < 2; ++it) {
      const int row = kw * 16 + it * 8 + (lane >> 3);
      const int blk = ((lane & 7) ^ row) & 7;
      glds16(gk + (size_t)row * K3 + blk * 8, Kdst + (kw * 16 + it * 8) * 64);
    }
    vreg = *(const bf16x8*)(qkvh + (rowBase + vkey) * K3 + 2 * DIM + h * DH + vdb);
#pragma unroll
    for (int e = 0; e < 8; ++e) Vt[0][sw(vdb + e, vkey)] = vreg[e];
    asm volatile("s_waitcnt vmcnt(0)" ::: "memory");
  }
  __syncthreads();

  for (int kt = 0; kt < nkt; ++kt) {
    const int kb = kt * 64;
    const int cb = kt & 1;
    const bool more = (kt + 1 < nkt);

    // ---- issue next tile's staging (into buf cb^1) before computing ----
    if (more) {
      const short* gk = gkbase + (rowBase + kb + 64) * K3;
      short* Kdst = (wv < 4) ? &Kh[cb ^ 1][0] : &Kl[cb ^ 1][0];
#pragma unroll
      for (int it = 0; it < 2; ++it) {
        const int row = kw * 16 + it * 8 + (lane >> 3);
        const int blk = ((lane & 7) ^ row) & 7;
        glds16(gk + (size_t)row * K3 + blk * 8, Kdst + (kw * 16 + it * 8) * 64);
      }
      vreg = *(const bf16x8*)(qkvh + (rowBase + kb + 64 + vkey) * K3 +
                              2 * DIM + h * DH + vdb);
    }

    // wave-uniform: does this wave's row range see any of these keys?
    const bool active = (kb <= qb + 16 * wv + 15);

    if (active) {
      // ---- S = Q K^T (pre-scaled), split-bf16 (hh + lh + hl) ----
      f32x4 s[4];
#pragma unroll
      for (int j = 0; j < 4; ++j) s[j] = (f32x4){0.f, 0.f, 0.f, 0.f};
      __builtin_amdgcn_s_setprio(1);
#pragma unroll
      for (int j = 0; j < 4; ++j) {
#pragma unroll
        for (int ks = 0; ks < 2; ++ks) {
          const bf16x8 kh = *(const bf16x8*)(&Kh[cb][sw(16 * j + l15, ks * 32 + quad * 8)]);
          const bf16x8 kl = *(const bf16x8*)(&Kl[cb][sw(16 * j + l15, ks * 32 + quad * 8)]);
          s[j] = __builtin_amdgcn_mfma_f32_16x16x32_bf16(qah[ks], kh, s[j], 0, 0, 0);
          s[j] = __builtin_amdgcn_mfma_f32_16x16x32_bf16(qal[ks], kh, s[j], 0, 0, 0);
          s[j] = __builtin_amdgcn_mfma_f32_16x16x32_bf16(qah[ks], kl, s[j], 0, 0, 0);
        }
      }
      __builtin_amdgcn_s_setprio(0);

      // ---- causal mask (diagonal iters only) + row max ----
      const int qrow0 = qb + 16 * wv + 4 * quad;
      const bool needmask = (kb + 63 > qb + 16 * wv);   // wave-uniform
      float p[4][4];
      float mt[4] = {-1e30f, -1e30f, -1e30f, -1e30f};
      if (needmask) {
#pragma unroll
        for (int j = 0; j < 4; ++j) {
          const int key = kb + 16 * j + l15;
#pragma unroll
          for (int r = 0; r < 4; ++r) {
            float sv = s[j][r];
            if (key > qrow0 + r) sv = NEGV;
            p[j][r] = sv;
            mt[r] = fmaxf(mt[r], sv);
          }
        }
      } else {
#pragma unroll
        for (int j = 0; j < 4; ++j)
#pragma unroll
          for (int r = 0; r < 4; ++r) {
            p[j][r] = s[j][r];
            mt[r] = fmaxf(mt[r], s[j][r]);
          }
      }
#pragma unroll
      for (int r = 0; r < 4; ++r) {
        mt[r] = fmaxf(mt[r], __shfl_xor(mt[r], 1));
        mt[r] = fmaxf(mt[r], __shfl_xor(mt[r], 2));
        mt[r] = fmaxf(mt[r], __shfl_xor(mt[r], 4));
        mt[r] = fmaxf(mt[r], __shfl_xor(mt[r], 8));
      }
      float alpha[4];
#pragma unroll
      for (int r = 0; r < 4; ++r) {
        const float mn = fmaxf(m_i[r], mt[r]);
        alpha[r] = __expf(m_i[r] - mn);
        m_i[r] = mn;
      }
      float ls[4] = {0.f, 0.f, 0.f, 0.f};
#pragma unroll
      for (int j = 0; j < 4; ++j)
#pragma unroll
        for (int r = 0; r < 4; ++r) {
          const float pe = __expf(p[j][r] - m_i[r]);
          ls[r] += pe;
          Ps[wv][sw(4 * quad + r, 16 * j + l15)] = f2bf(pe);  // fused store
        }
#pragma unroll
      for (int r = 0; r < 4; ++r) {
        ls[r] += __shfl_xor(ls[r], 1);
        ls[r] += __shfl_xor(ls[r], 2);
        ls[r] += __shfl_xor(ls[r], 4);
        ls[r] += __shfl_xor(ls[r], 8);
        l_i[r] = l_i[r] * alpha[r] + ls[r];
      }
#pragma unroll
      for (int jd = 0; jd < 4; ++jd)
#pragma unroll
        for (int r = 0; r < 4; ++r) O[jd][r] *= alpha[r];

      // ---- O += P V : A = P (same-wave LDS reload), B = Vt ----
      __builtin_amdgcn_s_setprio(1);
#pragma unroll
      for (int ks = 0; ks < 2; ++ks) {
        const bf16x8 pa = *(const bf16x8*)(&Ps[wv][sw(l15, ks * 32 + quad * 8)]);
#pragma unroll
        for (int jd = 0; jd < 4; ++jd) {
          const bf16x8 vb = *(const bf16x8*)(&Vt[cb][sw(16 * jd + l15, ks * 32 + quad * 8)]);
          O[jd] = __builtin_amdgcn_mfma_f32_16x16x32_bf16(pa, vb, O[jd], 0, 0, 0);
        }
      }
      __builtin_amdgcn_s_setprio(0);
    }

    // ---- finish staging: V scatter into buf cb^1, then single barrier ----
    if (more) {
      asm volatile("s_waitcnt vmcnt(0)" ::: "memory");  // vreg + K glds landed
#pragma unroll
      for (int e = 0; e < 8; ++e) Vt[cb ^ 1][sw(vdb + e, vkey)] = vreg[e];
    }
    __syncthreads();
  }

  // epilogue: O/l -> bf16 attn ws (C-layout scatter, once per block)
#pragma unroll
  for (int jd = 0; jd < 4; ++jd) {
#pragma unroll
    for (int r = 0; r < 4; ++r) {
      const int row = qb + 16 * wv + 4 * quad + r;
      attno[(rowBase + row) * DIM + h * DH + 16 * jd + l15] =
          __float2bfloat16(O[jd][r] / l_i[r]);
    }
  }
}

// ---------------------------------------------------------------------------
// Kernel 3a: out = attn @ w_out^T + b_out, both operands pre-bf16, glds
// staging (R1 qkv_gemm_pre structure, no in-loop conversion).
// ---------------------------------------------------------------------------
__global__ __launch_bounds__(256) void out_gemm_pre(
    const short* __restrict__ a,             // (8192, 1024) attn bf16
    const short* __restrict__ wob,           // (1024, 1024) bf16
    const float* __restrict__ bo,            // (1024) fp32
    float* __restrict__ out)                 // (8192, 1024) fp32
{
  __shared__ short As[128 * 32];
  __shared__ short Bs[128 * 32];

  const int t    = threadIdx.x;
  const int lane = t & 63;
  const int wv   = t >> 6;
  const int Mb   = blockIdx.y * 128;
  const int Nb   = blockIdx.x * 128;
  const int wr   = (wv >> 1) * 64;
  const int wc   = (wv & 1) * 64;
  const int l15  = lane & 15;
  const int lq   = lane >> 4;
  const int grow = lane >> 2;
  const int gcol = (lane & 3) * 8;

  f32x4 acc[4][4];
#pragma unroll
  for (int i = 0; i < 4; i++)
#pragma unroll
    for (int j = 0; j < 4; j++) acc[i][j] = (f32x4){0.f, 0.f, 0.f, 0.f};

  for (int k0 = 0; k0 < DIM; k0 += 32) {
    __syncthreads();
#pragma unroll
    for (int it = 0; it < 2; ++it) {
      const int r0 = wv * 32 + it * 16;
      glds16(a   + (size_t)(Mb + r0 + grow) * DIM + k0 + gcol, As + r0 * 32);
      glds16(wob + (size_t)(Nb + r0 + grow) * DIM + k0 + gcol, Bs + r0 * 32);
    }
    __syncthreads();

    bf16x8 af[4], bfr[4];
#pragma unroll
    for (int i = 0; i < 4; i++)
      af[i] = *(const bf16x8*)(As + (wr + i * 16 + l15) * 32 + lq * 8);
#pragma unroll
    for (int j = 0; j < 4; j++)
      bfr[j] = *(const bf16x8*)(Bs + (wc + j * 16 + l15) * 32 + lq * 8);
#pragma unroll
    for (int i = 0; i < 4; i++)
#pragma unroll
      for (int j = 0; j < 4; j++)
        acc[i][j] = __builtin_amdgcn_mfma_f32_16x16x32_bf16(af[i], bfr[j], acc[i][j], 0, 0, 0);
  }

#pragma unroll
  for (int j = 0; j < 4; j++) {
    const int col = Nb + wc + j * 16 + l15;
    const float bias = bo[col];
#pragma unroll
    for (int i = 0; i < 4; i++) {
#pragma unroll
      for (int r = 0; r < 4; r++) {
        const int row = Mb + wr + i * 16 + lq * 4 + r;
        out[(size_t)row * DIM + col] = acc[i][j][r] + bias;
      }
    }
  }
}

// ---------------------------------------------------------------------------
// Kernel 3b (fallback): out = attn @ w_out^T + b_out, fp32 W in-loop cvt.
// ---------------------------------------------------------------------------
__global__ __launch_bounds__(256) void out_gemm(
    const __hip_bfloat16* __restrict__ a,    // (8192, 1024) attn, bf16
    const float* __restrict__ wo,            // (1024, 1024) fp32
    const float* __restrict__ bo,            // (1024) fp32
    float* __restrict__ out)                 // (8192, 1024) fp32
{
  __shared__ short As[128 * 32];
  __shared__ short Bs[128 * 32];

  const int t    = threadIdx.x;
  const int lane = t & 63;
  const int wv   = t >> 6;
  const int Mb   = blockIdx.y * 128;
  const int Nb   = blockIdx.x * 128;
  const int wr   = (wv >> 1) * 64;
  const int wc   = (wv & 1) * 64;
  const int l15  = lane & 15;
  const int lq   = lane >> 4;
  const int srow = wv * 16 + (lane >> 2);
  const int scol = (lane & 3) * 8;

  f32x4 acc[4][4];
#pragma unroll
  for (int i = 0; i < 4; i++)
#pragma unroll
    for (int j = 0; j < 4; j++) acc[i][j] = (f32x4){0.f, 0.f, 0.f, 0.f};

  for (int k0 = 0; k0 < DIM; k0 += 32) {
    bf16x8 areg[2], breg[2];
#pragma unroll
    for (int it = 0; it < 2; ++it) {
      areg[it] = *(const bf16x8*)(a + (size_t)(Mb + it * 64 + srow) * DIM + k0 + scol);
      const float* bp = wo + (size_t)(Nb + it * 64 + srow) * DIM + k0 + scol;
      const float4 b0 = *(const float4*)(bp);
      const float4 b1 = *(const float4*)(bp + 4);
      const float bf8[8] = {b0.x, b0.y, b0.z, b0.w, b1.x, b1.y, b1.z, b1.w};
#pragma unroll
      for (int e = 0; e < 8; e++) breg[it][e] = f2bf(bf8[e]);
    }
    __syncthreads();
#pragma unroll
    for (int it = 0; it < 2; ++it) {
      *(bf16x8*)(As + (it * 64 + srow) * 32 + scol) = areg[it];
      *(bf16x8*)(Bs + (it * 64 + srow) * 32 + scol) = breg[it];
    }
    __syncthreads();

    bf16x8 af[4], bfr[4];
#pragma unroll
    for (int i = 0; i < 4; i++)
      af[i] = *(const bf16x8*)(As + (wr + i * 16 + l15) * 32 + lq * 8);
#pragma unroll
    for (int j = 0; j < 4; j++)
      bfr[j] = *(const bf16x8*)(Bs + (wc + j * 16 + l15) * 32 + lq * 8);
#pragma unroll
    for (int i = 0; i < 4; i++)
#pragma unroll
      for (int j = 0; j < 4; j++)
        acc[i][j] = __builtin_amdgcn_mfma_f32_16x16x32_bf16(af[i], bfr[j], acc[i][j], 0, 0, 0);
  }

#pragma unroll
  for (int j = 0; j < 4; j++) {
    const int col = Nb + wc + j * 16 + l15;
    const float bias = bo[col];
#pragma unroll
    for (int i = 0; i < 4; i++) {
#pragma unroll
      for (int r = 0; r < 4; r++) {
        const int row = Mb + wr + i * 16 + lq * 4 + r;
        out[(size_t)row * DIM + col] = acc[i][j][r] + bias;
      }
    }
  }
}

// ---------------------------------------------------------------------------
extern "C" void kernel_launch(void* const* d_in, const int* in_sizes, int n_in,
                              void* d_out, int out_size, void* d_ws, size_t ws_size,
                              hipStream_t stream) {
  const float* q    = (const float*)d_in[0];
  const float* k    = (const float*)d_in[1];
  const float* v    = (const float*)d_in[2];
  const float* wqkv = (const float*)d_in[3];
  const float* bqkv = (const float*)d_in[4];
  const float* wout = (const float*)d_in[5];
  const float* bout = (const float*)d_in[6];

  // ws layout:
  //   [0,48MB)    qkv_hi bf16 (8192x3072)
  //   [48,96MB)   qkv_lo bf16 (8192x3072; only q,k cols written/read)
  //   [96MB,...)  prep path: A_hi(48) A_lo(48) B_hi(18) B_lo(18) = +132MB
  //               attn bf16 (16MB) aliases A_hi[0:16MB] (A region dead after
  //               qkv_gemm_8p); wout bf16 (2MB) aliases A_hi[16:18MB].
  //   fallback:   attn bf16 at 96MB (112MB total)
  const size_t PLANE = (size_t)MROWS * K3 * 2;        // 50331648 B
  const size_t BPLN  = (size_t)K3 * K3 * 2;           // 18874368 B
  short* qh = (short*)d_ws;
  short* ql = (short*)((char*)d_ws + PLANE);
  char*  p2 = (char*)d_ws + 2 * PLANE;                // offset 96 MB
  __hip_bfloat16* attnws = (__hip_bfloat16*)p2;

  const size_t NEED = 2 * PLANE + 2 * PLANE + 2 * BPLN;  // 228 MB

  if (ws_size >= NEED) {
    short* Ah = (short*)p2;
    short* Al = Ah + (size_t)MROWS * K3;
    short* Bh = Al + (size_t)MROWS * K3;
    short* Bl = Bh + (size_t)K3 * K3;
    short* wob = (short*)(p2 + (size_t)MROWS * DIM * 2);  // after attnws
    prep_x<<<4096, 256, 0, stream>>>(q, k, v, Ah, Al);
    prep_w<<<2048, 256, 0, stream>>>(wqkv, Bh, Bl);
    qkv_gemm_8p<<<dim3(256), 512, 0, stream>>>(Ah, Al, Bh, Bl, bqkv, qh, ql);
    prep_wo<<<256, 256, 0, stream>>>(wout, wob);          // A region now dead
    attn_fwd<<<dim3(4 * HEADS * (SEQ / 128)), 512, 0, stream>>>(qh, ql, attnws);
    out_gemm_pre<<<dim3(DIM / 128, MROWS / 128), 256, 0, stream>>>(
        (const short*)attnws, wob, bout, (float*)d_out);
  } else {
    qkv_gemm_fly<<<dim3(K3 / 128, MROWS / 128), 256, 0, stream>>>(
        q, k, v, wqkv, bqkv, qh, ql);
    attn_fwd<<<dim3(4 * HEADS * (SEQ / 128)), 512, 0, stream>>>(qh, ql, attnws);
    out_gemm<<<dim3(DIM / 128, MROWS / 128), 256, 0, stream>>>(attnws, wout, bout,
                                                               (float*)d_out);
  }
}

// Round 6
// 672.715 us; speedup vs baseline: 1.2194x; 1.1461x over previous
//
#include <hip/hip_runtime.h>
#include <hip/hip_bf16.h>

// Problem constants: B=4, N=2048, D=1024, H=16, dh=64. All I/O fp32.
#define SEQ   2048
#define DIM   1024
#define HEADS 16
#define DH    64
#define MROWS 8192            // B*N
#define K3    3072            // 3*D
#define NEGV  (-32767.0f)     // -2^15+1, matches reference mask constant
#define SCALE 8.0f            // sqrt(dh) — reference MULTIPLIES by sqrt(d)

typedef __attribute__((ext_vector_type(8))) short bf16x8;
typedef __attribute__((ext_vector_type(4))) float f32x4;

// bf16 round-to-nearest-even via bit ops (finite inputs only)
__device__ __forceinline__ short f2bf(float x) {
  union { float f; unsigned u; } v; v.f = x;
  unsigned r = v.u + 0x7FFF + ((v.u >> 16) & 1);
  return (short)(r >> 16);
}
__device__ __forceinline__ float bf2f(short s) {
  union { float f; unsigned u; } v; v.u = ((unsigned)(unsigned short)s) << 16;
  return v.f;
}
__device__ __forceinline__ void split1(float x, short& h, short& l) {
  h = f2bf(x);
  l = f2bf(x - bf2f(h));
}
__device__ __forceinline__ void cvt_split8(const float4 a, const float4 b,
                                           bf16x8& hi, bf16x8& lo) {
  const float f[8] = {a.x, a.y, a.z, a.w, b.x, b.y, b.z, b.w};
#pragma unroll
  for (int i = 0; i < 8; i++) {
    short h, l; split1(f[i], h, l);
    hi[i] = h; lo[i] = l;
  }
}

// async global->LDS, 16B per lane. LDS dest is wave-uniform base; HW writes
// lane l at base + l*16 bytes. Global src is per-lane.
__device__ __forceinline__ void glds16(const void* g, void* l) {
  __builtin_amdgcn_global_load_lds(
      (const __attribute__((address_space(1))) void*)g,
      (__attribute__((address_space(3))) void*)l, 16, 0, 0);
}

// XOR-swizzled LDS index (shorts) for 64-col row-major tiles: 8-short (16B)
// blocks permuted by row&7 -> ds_read_b128-able fragments, spread banks.
__device__ __forceinline__ int sw(int row, int col) {
  return row * 64 + ((((col >> 3) ^ row) & 7) << 3) + (col & 7);
}

// ---------------------------------------------------------------------------
// Prep kernels: one-time fp32 -> bf16 (hi/lo RNE split where needed).
// ---------------------------------------------------------------------------
__global__ __launch_bounds__(256) void prep_x(
    const float* __restrict__ q, const float* __restrict__ k,
    const float* __restrict__ v,
    short* __restrict__ ah, short* __restrict__ al)  // (8192, 3072) bf16 each
{
  const int n = MROWS * (K3 / 4);                    // float4 work items
  for (int i = blockIdx.x * 256 + threadIdx.x; i < n; i += gridDim.x * 256) {
    const int r  = i / 768;                          // 3072/4 cols per row
    const int c4 = i - r * 768;
    const float* src = (c4 < 256) ? q : ((c4 < 512) ? k : v);
    const int cc = c4 & 255;
    const float4 f = *(const float4*)(src + ((size_t)r * 256 + cc) * 4);
    const float fa[4] = {f.x, f.y, f.z, f.w};
    short hi[4], lo[4];
#pragma unroll
    for (int e = 0; e < 4; ++e) split1(fa[e], hi[e], lo[e]);
    const size_t o = (size_t)r * K3 + c4 * 4;
    *(short4*)(ah + o) = make_short4(hi[0], hi[1], hi[2], hi[3]);
    *(short4*)(al + o) = make_short4(lo[0], lo[1], lo[2], lo[3]);
  }
}

__global__ __launch_bounds__(256) void prep_w(
    const float* __restrict__ w,                     // (3072,3072) fp32
    short* __restrict__ bh, short* __restrict__ bl)  // bf16 each
{
  const int n = (K3 * K3) / 4;
  for (int i = blockIdx.x * 256 + threadIdx.x; i < n; i += gridDim.x * 256) {
    const float4 f = ((const float4*)w)[i];
    const float fa[4] = {f.x, f.y, f.z, f.w};
    short hi[4], lo[4];
#pragma unroll
    for (int e = 0; e < 4; ++e) split1(fa[e], hi[e], lo[e]);
    ((short4*)bh)[i] = make_short4(hi[0], hi[1], hi[2], hi[3]);
    ((short4*)bl)[i] = make_short4(lo[0], lo[1], lo[2], lo[3]);
  }
}

__global__ __launch_bounds__(256) void prep_wo(
    const float* __restrict__ w,                     // (1024,1024) fp32
    short* __restrict__ wb)                          // bf16
{
  const int n = (DIM * DIM) / 4;
  for (int i = blockIdx.x * 256 + threadIdx.x; i < n; i += gridDim.x * 256) {
    const float4 f = ((const float4*)w)[i];
    ((short4*)wb)[i] = make_short4(f2bf(f.x), f2bf(f.y), f2bf(f.z), f2bf(f.w));
  }
}

// ---------------------------------------------------------------------------
// Kernel 1a: qkv GEMM, 256x256 tiles, 8-phase counted-vmcnt schedule.
// Grid = 256 blocks; each block computes ONE heavy (q,k cols; packed-K 144
// tiles) 256x256 tile, then HALF of one light (v cols; 48 tiles) 256-wide
// tile (128 rows) -> uniform 168 tile-equivalents per block (load-balanced).
// ---------------------------------------------------------------------------
__device__ __forceinline__ void stage_half(const short* __restrict__ src,
                                           short* dst, int wv, int lane) {
  // half-tile = 128 rows x 64 cols bf16 = 16KB; wave wv covers 2x1KB pieces.
  // LDS dest linear; source col-block pre-swizzled (involution cb^row&7).
#pragma unroll
  for (int e = 0; e < 2; ++e) {
    const int idx = (wv * 2 + e) * 512 + lane * 8;   // linear short index
    const int row = idx >> 6;
    const int cb  = (idx >> 3) & 7;
    const int cbs = (cb ^ row) & 7;
    glds16(src + (size_t)row * K3 + cbs * 8, dst + (wv * 2 + e) * 512);
  }
}

__global__ __launch_bounds__(512, 2) void qkv_gemm_8p(
    const short* __restrict__ Ah, const short* __restrict__ Al,
    const short* __restrict__ Bh, const short* __restrict__ Bl,
    const float* __restrict__ bqkv,
    short* __restrict__ qh, short* __restrict__ ql)
{
  __shared__ short L[2][4][8192];   // [buf][A0,A1,B0,B1][128*64], 128 KB

  const int t    = threadIdx.x;
  const int lane = t & 63;
  const int wv   = t >> 6;          // 0..7
  const int wr   = wv >> 2;         // 0..1  (M half)
  const int wc   = wv & 3;          // 0..3  (N slice)
  const int l15  = lane & 15;
  const int lq   = lane >> 4;

  // ======================= HEAVY: q,k columns =======================
  // XCD-chunked bijective swizzle over 256 heavy tiles (32 M x 8 N).
  const int w  = (blockIdx.x & 7) * 32 + (blockIdx.x >> 3);
  const int Mb = (w & 31) * 256;
  const int Nb = (w >> 5) * 256;    // 0..1792 (q,k cols)
  const int nt = 144;               // packed-K

  // tile kt -> source for half h (0,1 = A halves; 2,3 = B halves)
  auto tsrc = [&](int kt, int h) -> const short* {
    kt = (kt < nt - 1) ? kt : (nt - 1);
    const int seg = (kt >= 96) ? 2 : ((kt >= 48) ? 1 : 0);
    const int k0  = (kt - seg * 48) * 64;
    if (h < 2) {
      const short* Apl = (seg == 2) ? Al : Ah;
      return Apl + (size_t)(Mb + h * 128) * K3 + k0;
    }
    const short* Bpl = (seg == 1) ? Bl : Bh;
    return Bpl + (size_t)(Nb + (h - 2) * 128) * K3 + k0;
  };

  f32x4 acc[8][4];
#pragma unroll
  for (int i = 0; i < 8; i++)
#pragma unroll
    for (int j = 0; j < 4; j++) acc[i][j] = (f32x4){0.f, 0.f, 0.f, 0.f};

  // prologue: tile 0 -> buf0 (all 4 halves), tile 1 -> buf1 B halves
  stage_half(tsrc(0, 0), &L[0][0][0], wv, lane);
  stage_half(tsrc(0, 1), &L[0][1][0], wv, lane);
  stage_half(tsrc(0, 2), &L[0][2][0], wv, lane);
  stage_half(tsrc(0, 3), &L[0][3][0], wv, lane);
  stage_half(tsrc(1, 2), &L[1][2][0], wv, lane);
  stage_half(tsrc(1, 3), &L[1][3][0], wv, lane);
  asm volatile("s_waitcnt vmcnt(4)" ::: "memory");   // buf0 landed
  __builtin_amdgcn_s_barrier();

  bf16x8 bfr[4][2];                 // B frags, live across each 4-phase group

  for (int kp = 0; kp < nt; kp += 2) {
#pragma unroll
    for (int p = 0; p < 8; ++p) {
      const int buf = p >> 2;
      const int qtr = p & 3;
      const int mi0 = qtr * 2;

      if (qtr == 0) {
#pragma unroll
        for (int ni = 0; ni < 4; ++ni)
#pragma unroll
          for (int ks = 0; ks < 2; ++ks)
            bfr[ni][ks] = *(const bf16x8*)(
                &L[buf][2 + (wc >> 1)][sw((wc & 1) * 64 + ni * 16 + l15,
                                          ks * 32 + lq * 8)]);
      }
      bf16x8 afr[2][2];
#pragma unroll
      for (int m = 0; m < 2; ++m)
#pragma unroll
        for (int ks = 0; ks < 2; ++ks)
          afr[m][ks] = *(const bf16x8*)(
              &L[buf][wr][sw((mi0 + m) * 16 + l15, ks * 32 + lq * 8)]);

      {
        const int SB[8] = {1, 1, 0, 0, 0, 0, 1, 1};
        const int SH[8] = {0, 1, 2, 3, 0, 1, 2, 3};
        const int SD[8] = {1, 1, 2, 2, 2, 2, 3, 3};
        stage_half(tsrc(kp + SD[p], SH[p]), &L[SB[p]][SH[p]][0], wv, lane);
      }

      if (qtr == 3) asm volatile("s_waitcnt vmcnt(4)" ::: "memory");
      __builtin_amdgcn_s_barrier();
      asm volatile("s_waitcnt lgkmcnt(0)" ::: "memory");
      __builtin_amdgcn_sched_barrier(0);

      __builtin_amdgcn_s_setprio(1);
#pragma unroll
      for (int m = 0; m < 2; ++m)
#pragma unroll
        for (int ni = 0; ni < 4; ++ni)
#pragma unroll
          for (int ks = 0; ks < 2; ++ks)
            acc[mi0 + m][ni] = __builtin_amdgcn_mfma_f32_16x16x32_bf16(
                afr[m][ks], bfr[ni][ks], acc[mi0 + m][ni], 0, 0, 0);
      __builtin_amdgcn_s_setprio(0);
      __builtin_amdgcn_s_barrier();
    }
  }

  // heavy epilogue: bias + bf16 hi/lo split output
#pragma unroll
  for (int ni = 0; ni < 4; ++ni) {
    const int col = Nb + wc * 64 + ni * 16 + l15;
    const float bias = bqkv[col];
#pragma unroll
    for (int mi = 0; mi < 8; ++mi) {
#pragma unroll
      for (int r = 0; r < 4; ++r) {
        const int row = Mb + wr * 128 + mi * 16 + lq * 4 + r;
        const float xv = acc[mi][ni][r] + bias;
        const short hh = f2bf(xv);
        qh[(size_t)row * K3 + col] = hh;
        ql[(size_t)row * K3 + col] = f2bf(xv - bf2f(hh));
      }
    }
  }

  // ======================= LIGHT: v columns (half tile) =======================
  asm volatile("s_waitcnt vmcnt(0)" ::: "memory");
  __builtin_amdgcn_s_barrier();

  const int lt  = blockIdx.x >> 1;                   // 0..127 light tiles
  const int MbL = (lt & 31) * 256 + (blockIdx.x & 1) * 128;
  const int NbL = 2 * DIM + (lt >> 5) * 256;

  auto tsrcL = [&](int kt, int h) -> const short* {
    kt = (kt < 47) ? kt : 47;
    const int k0 = kt * 64;
    if (h == 0) return Ah + (size_t)MbL * K3 + k0;
    return Bh + (size_t)(NbL + (h - 2) * 128) * K3 + k0;
  };

#pragma unroll
  for (int i = 0; i < 4; i++)
#pragma unroll
    for (int j = 0; j < 4; j++) acc[i][j] = (f32x4){0.f, 0.f, 0.f, 0.f};

  stage_half(tsrcL(0, 0), &L[0][0][0], wv, lane);
  stage_half(tsrcL(0, 2), &L[0][2][0], wv, lane);
  stage_half(tsrcL(0, 3), &L[0][3][0], wv, lane);
  stage_half(tsrcL(1, 2), &L[1][2][0], wv, lane);
  stage_half(tsrcL(1, 3), &L[1][3][0], wv, lane);
  asm volatile("s_waitcnt vmcnt(4)" ::: "memory");
  __builtin_amdgcn_s_barrier();

  for (int kp = 0; kp < 48; kp += 2) {
#pragma unroll
    for (int p = 0; p < 4; ++p) {
      const int buf = p >> 1;
      const int mh  = p & 1;

      if (mh == 0) {
#pragma unroll
        for (int ni = 0; ni < 4; ++ni)
#pragma unroll
          for (int ks = 0; ks < 2; ++ks)
            bfr[ni][ks] = *(const bf16x8*)(
                &L[buf][2 + (wc >> 1)][sw((wc & 1) * 64 + ni * 16 + l15,
                                          ks * 32 + lq * 8)]);
      }
      bf16x8 afr[2][2];
#pragma unroll
      for (int m = 0; m < 2; ++m)
#pragma unroll
        for (int ks = 0; ks < 2; ++ks)
          afr[m][ks] = *(const bf16x8*)(
              &L[buf][0][sw(wr * 64 + (mh * 2 + m) * 16 + l15,
                            ks * 32 + lq * 8)]);

      if (p == 0) {
        stage_half(tsrcL(kp + 1, 0), &L[1][0][0], wv, lane);
      } else if (p == 1) {
        stage_half(tsrcL(kp + 2, 2), &L[0][2][0], wv, lane);
        stage_half(tsrcL(kp + 2, 3), &L[0][3][0], wv, lane);
      } else if (p == 2) {
        stage_half(tsrcL(kp + 2, 0), &L[0][0][0], wv, lane);
      } else {
        stage_half(tsrcL(kp + 3, 2), &L[1][2][0], wv, lane);
        stage_half(tsrcL(kp + 3, 3), &L[1][3][0], wv, lane);
      }

      if (mh == 1) asm volatile("s_waitcnt vmcnt(4)" ::: "memory");
      __builtin_amdgcn_s_barrier();
      asm volatile("s_waitcnt lgkmcnt(0)" ::: "memory");
      __builtin_amdgcn_sched_barrier(0);

      __builtin_amdgcn_s_setprio(1);
#pragma unroll
      for (int m = 0; m < 2; ++m)
#pragma unroll
        for (int ni = 0; ni < 4; ++ni)
#pragma unroll
          for (int ks = 0; ks < 2; ++ks)
            acc[mh * 2 + m][ni] = __builtin_amdgcn_mfma_f32_16x16x32_bf16(
                afr[m][ks], bfr[ni][ks], acc[mh * 2 + m][ni], 0, 0, 0);
      __builtin_amdgcn_s_setprio(0);
      __builtin_amdgcn_s_barrier();
    }
  }

#pragma unroll
  for (int ni = 0; ni < 4; ++ni) {
    const int col = NbL + wc * 64 + ni * 16 + l15;
    const float bias = bqkv[col];
#pragma unroll
    for (int mi = 0; mi < 4; ++mi) {
#pragma unroll
      for (int r = 0; r < 4; ++r) {
        const int row = MbL + wr * 64 + mi * 16 + lq * 4 + r;
        qh[(size_t)row * K3 + col] = f2bf(acc[mi][ni][r] + bias);
      }
    }
  }
}

// ---------------------------------------------------------------------------
// Kernel 1b (fallback, ws too small for prep): in-loop cvt, hi/lo output.
// ---------------------------------------------------------------------------
__global__ __launch_bounds__(256) void qkv_gemm_fly(
    const float* __restrict__ q,
    const float* __restrict__ k,
    const float* __restrict__ v,
    const float* __restrict__ wqkv,
    const float* __restrict__ bqkv,
    short* __restrict__ qh, short* __restrict__ ql)
{
  __shared__ short Ash[128 * 32];
  __shared__ short Asl[128 * 32];
  __shared__ short Bsh[128 * 32];
  __shared__ short Bsl[128 * 32];

  const int t    = threadIdx.x;
  const int lane = t & 63;
  const int wv   = t >> 6;
  const int Mb   = blockIdx.y * 128;
  const int Nb   = blockIdx.x * 128;
  const bool prec = (Nb < 2 * DIM);
  const int wr   = (wv >> 1) * 64;
  const int wc   = (wv & 1) * 64;
  const int l15  = lane & 15;
  const int lq   = lane >> 4;
  const int srow = wv * 16 + (lane >> 2);
  const int scol = (lane & 3) * 8;

  f32x4 acc[4][4];
#pragma unroll
  for (int i = 0; i < 4; i++)
#pragma unroll
    for (int j = 0; j < 4; j++) acc[i][j] = (f32x4){0.f, 0.f, 0.f, 0.f};

  for (int k0 = 0; k0 < K3; k0 += 32) {
    const float* src = (k0 < DIM) ? q : ((k0 < 2 * DIM) ? k : v);
    const int koff = (k0 & (DIM - 1)) + scol;

    bf16x8 ah[2], al[2], bh[2], bl[2];
#pragma unroll
    for (int it = 0; it < 2; ++it) {
      const float* ap = src + (size_t)(Mb + it * 64 + srow) * DIM + koff;
      cvt_split8(*(const float4*)(ap), *(const float4*)(ap + 4), ah[it], al[it]);
      const float* bp = wqkv + (size_t)(Nb + it * 64 + srow) * K3 + k0 + scol;
      cvt_split8(*(const float4*)(bp), *(const float4*)(bp + 4), bh[it], bl[it]);
    }
    __syncthreads();
#pragma unroll
    for (int it = 0; it < 2; ++it) {
      *(bf16x8*)(Ash + (it * 64 + srow) * 32 + scol) = ah[it];
      *(bf16x8*)(Bsh + (it * 64 + srow) * 32 + scol) = bh[it];
      if (prec) {
        *(bf16x8*)(Asl + (it * 64 + srow) * 32 + scol) = al[it];
        *(bf16x8*)(Bsl + (it * 64 + srow) * 32 + scol) = bl[it];
      }
    }
    __syncthreads();

    bf16x8 afh[4], bfh[4];
#pragma unroll
    for (int i = 0; i < 4; i++)
      afh[i] = *(const bf16x8*)(Ash + (wr + i * 16 + l15) * 32 + lq * 8);
#pragma unroll
    for (int j = 0; j < 4; j++)
      bfh[j] = *(const bf16x8*)(Bsh + (wc + j * 16 + l15) * 32 + lq * 8);
#pragma unroll
    for (int i = 0; i < 4; i++)
#pragma unroll
      for (int j = 0; j < 4; j++)
        acc[i][j] = __builtin_amdgcn_mfma_f32_16x16x32_bf16(afh[i], bfh[j], acc[i][j], 0, 0, 0);

    if (prec) {
      bf16x8 afl[4], bfl[4];
#pragma unroll
      for (int i = 0; i < 4; i++)
        afl[i] = *(const bf16x8*)(Asl + (wr + i * 16 + l15) * 32 + lq * 8);
#pragma unroll
      for (int j = 0; j < 4; j++)
        bfl[j] = *(const bf16x8*)(Bsl + (wc + j * 16 + l15) * 32 + lq * 8);
#pragma unroll
      for (int i = 0; i < 4; i++)
#pragma unroll
        for (int j = 0; j < 4; j++) {
          acc[i][j] = __builtin_amdgcn_mfma_f32_16x16x32_bf16(afh[i], bfl[j], acc[i][j], 0, 0, 0);
          acc[i][j] = __builtin_amdgcn_mfma_f32_16x16x32_bf16(afl[i], bfh[j], acc[i][j], 0, 0, 0);
        }
    }
  }

#pragma unroll
  for (int j = 0; j < 4; j++) {
    const int col = Nb + wc + j * 16 + l15;
    const float bias = bqkv[col];
#pragma unroll
    for (int i = 0; i < 4; i++) {
#pragma unroll
      for (int r = 0; r < 4; r++) {
        const int row = Mb + wr + i * 16 + lq * 4 + r;
        const float xv = acc[i][j][r] + bias;
        const short hh = f2bf(xv);
        qh[(size_t)row * K3 + col] = hh;
        if (prec) ql[(size_t)row * K3 + col] = f2bf(xv - bf2f(hh));
      }
    }
  }
}

// ---------------------------------------------------------------------------
// Kernel 2: MFMA flash attention, 128-row q-tiles, 8 waves, double-buffered
// K/V staging, ONE barrier/iter. This round:
//  - TWO q-tiles per block ({15-g, g}: Sum(qt)=15 for every g -> perfectly
//    balanced 34 iters/block) -> K/V streamed 8x per head instead of 16x.
//  - bx = g*64 + bh: all 8 blocks of one (b,h) share an XCD under
//    round-robin dispatch (XCD = bx%8 = bh%8) -> concurrent KV footprint
//    6MB/XCD (was 25-49MB) -> K/V reads become L2 hits.
// Per-row math sequence identical -> bit-identical output.
// ---------------------------------------------------------------------------
__global__ __launch_bounds__(512, 4) void attn_fwd(
    const short* __restrict__ qkvh,         // (8192, 3072) bf16 hi
    const short* __restrict__ qkvl,         // (8192, 3072) bf16 lo (q,k cols)
    __hip_bfloat16* __restrict__ attno)     // (8192, 1024) bf16
{
  __shared__ short Kh[2][4096], Kl[2][4096], Vt[2][4096];  // 48 KB
  __shared__ short Ps[8][1024];                            // 16 KB

  const int bx = blockIdx.x;
  const int g  = bx >> 6;                   // 0..7 (q-tile group)
  const int bh = bx & 63;                   // XCD = bh & 7 (co-location)
  const int h  = bh & 15;
  const int b  = bh >> 4;

  const int t    = threadIdx.x;
  const int lane = t & 63;
  const int wv   = t >> 6;                  // 0..7
  const int l15  = lane & 15;
  const int quad = lane >> 4;
  const size_t rowBase = (size_t)b * SEQ;

  // K staging: waves 0-3 hi plane, 4-7 lo plane; 2 glds16 each.
  const short* gkbase = ((wv < 4) ? qkvh : qkvl) + DIM + h * DH;
  const int kw = wv & 3;
  // V staging: 512 threads x 8 shorts = 64x64 tile, one reg load each.
  const int vkey = t >> 3;
  const int vdb  = (t & 7) * 8;

#pragma unroll 1
  for (int pass = 0; pass < 2; ++pass) {
    const int qt = pass ? g : (15 - g);     // heavy tile first
    const int qb = qt * 128;

    // Q A-fragments: rows qb + 16*wv + l15 (load once per pass), pre-scaled
    // by 8 (exact: x8 is an exponent shift for every bf16 value incl. +-0).
    bf16x8 qah[2], qal[2];
    {
      const size_t qoff = (rowBase + qb + 16 * wv + l15) * K3 + h * DH;
#pragma unroll
      for (int ks = 0; ks < 2; ++ks) {
        qah[ks] = *(const bf16x8*)(qkvh + qoff + ks * 32 + quad * 8);
        qal[ks] = *(const bf16x8*)(qkvl + qoff + ks * 32 + quad * 8);
#pragma unroll
        for (int e = 0; e < 8; ++e) {
          qah[ks][e] = f2bf(SCALE * bf2f(qah[ks][e]));
          qal[ks][e] = f2bf(SCALE * bf2f(qal[ks][e]));
        }
      }
    }

    float m_i[4], l_i[4];
    f32x4 O[4];
#pragma unroll
    for (int r = 0; r < 4; ++r) { m_i[r] = -1e30f; l_i[r] = 0.f; }
#pragma unroll
    for (int jd = 0; jd < 4; ++jd) O[jd] = (f32x4){0.f, 0.f, 0.f, 0.f};

    const int nkt = 2 * qt + 2;             // causal: keys <= qb+127
    bf16x8 vreg;

    // ---- prologue: stage tile 0 into buf 0 ----
    {
      const short* gk = gkbase + rowBase * K3;
      short* Kdst = (wv < 4) ? &Kh[0][0] : &Kl[0][0];
#pragma unroll
      for (int it = 0; it < 2; ++it) {
        const int row = kw * 16 + it * 8 + (lane >> 3);
        const int blk = ((lane & 7) ^ row) & 7;
        glds16(gk + (size_t)row * K3 + blk * 8, Kdst + (kw * 16 + it * 8) * 64);
      }
      vreg = *(const bf16x8*)(qkvh + (rowBase + vkey) * K3 + 2 * DIM + h * DH + vdb);
#pragma unroll
      for (int e = 0; e < 8; ++e) Vt[0][sw(vdb + e, vkey)] = vreg[e];
      asm volatile("s_waitcnt vmcnt(0)" ::: "memory");
    }
    __syncthreads();

    for (int kt = 0; kt < nkt; ++kt) {
      const int kb = kt * 64;
      const int cb = kt & 1;
      const bool more = (kt + 1 < nkt);

      // ---- issue next tile's staging (into buf cb^1) before computing ----
      if (more) {
        const short* gk = gkbase + (rowBase + kb + 64) * K3;
        short* Kdst = (wv < 4) ? &Kh[cb ^ 1][0] : &Kl[cb ^ 1][0];
#pragma unroll
        for (int it = 0; it < 2; ++it) {
          const int row = kw * 16 + it * 8 + (lane >> 3);
          const int blk = ((lane & 7) ^ row) & 7;
          glds16(gk + (size_t)row * K3 + blk * 8, Kdst + (kw * 16 + it * 8) * 64);
        }
        vreg = *(const bf16x8*)(qkvh + (rowBase + kb + 64 + vkey) * K3 +
                                2 * DIM + h * DH + vdb);
      }

      // wave-uniform: does this wave's row range see any of these keys?
      const bool active = (kb <= qb + 16 * wv + 15);

      if (active) {
        // ---- S = Q K^T (pre-scaled), split-bf16 (hh + lh + hl) ----
        f32x4 s[4];
#pragma unroll
        for (int j = 0; j < 4; ++j) s[j] = (f32x4){0.f, 0.f, 0.f, 0.f};
        __builtin_amdgcn_s_setprio(1);
#pragma unroll
        for (int j = 0; j < 4; ++j) {
#pragma unroll
          for (int ks = 0; ks < 2; ++ks) {
            const bf16x8 kh = *(const bf16x8*)(&Kh[cb][sw(16 * j + l15, ks * 32 + quad * 8)]);
            const bf16x8 kl = *(const bf16x8*)(&Kl[cb][sw(16 * j + l15, ks * 32 + quad * 8)]);
            s[j] = __builtin_amdgcn_mfma_f32_16x16x32_bf16(qah[ks], kh, s[j], 0, 0, 0);
            s[j] = __builtin_amdgcn_mfma_f32_16x16x32_bf16(qal[ks], kh, s[j], 0, 0, 0);
            s[j] = __builtin_amdgcn_mfma_f32_16x16x32_bf16(qah[ks], kl, s[j], 0, 0, 0);
          }
        }
        __builtin_amdgcn_s_setprio(0);

        // ---- causal mask (diagonal iters only) + row max ----
        const int qrow0 = qb + 16 * wv + 4 * quad;
        const bool needmask = (kb + 63 > qb + 16 * wv);   // wave-uniform
        float p[4][4];
        float mt[4] = {-1e30f, -1e30f, -1e30f, -1e30f};
        if (needmask) {
#pragma unroll
          for (int j = 0; j < 4; ++j) {
            const int key = kb + 16 * j + l15;
#pragma unroll
            for (int r = 0; r < 4; ++r) {
              float sv = s[j][r];
              if (key > qrow0 + r) sv = NEGV;
              p[j][r] = sv;
              mt[r] = fmaxf(mt[r], sv);
            }
          }
        } else {
#pragma unroll
          for (int j = 0; j < 4; ++j)
#pragma unroll
            for (int r = 0; r < 4; ++r) {
              p[j][r] = s[j][r];
              mt[r] = fmaxf(mt[r], s[j][r]);
            }
        }
#pragma unroll
        for (int r = 0; r < 4; ++r) {
          mt[r] = fmaxf(mt[r], __shfl_xor(mt[r], 1));
          mt[r] = fmaxf(mt[r], __shfl_xor(mt[r], 2));
          mt[r] = fmaxf(mt[r], __shfl_xor(mt[r], 4));
          mt[r] = fmaxf(mt[r], __shfl_xor(mt[r], 8));
        }
        float alpha[4];
#pragma unroll
        for (int r = 0; r < 4; ++r) {
          const float mn = fmaxf(m_i[r], mt[r]);
          alpha[r] = __expf(m_i[r] - mn);
          m_i[r] = mn;
        }
        float ls[4] = {0.f, 0.f, 0.f, 0.f};
#pragma unroll
        for (int j = 0; j < 4; ++j)
#pragma unroll
          for (int r = 0; r < 4; ++r) {
            const float pe = __expf(p[j][r] - m_i[r]);
            ls[r] += pe;
            Ps[wv][sw(4 * quad + r, 16 * j + l15)] = f2bf(pe);  // fused store
          }
#pragma unroll
        for (int r = 0; r < 4; ++r) {
          ls[r] += __shfl_xor(ls[r], 1);
          ls[r] += __shfl_xor(ls[r], 2);
          ls[r] += __shfl_xor(ls[r], 4);
          ls[r] += __shfl_xor(ls[r], 8);
          l_i[r] = l_i[r] * alpha[r] + ls[r];
        }
#pragma unroll
        for (int jd = 0; jd < 4; ++jd)
#pragma unroll
          for (int r = 0; r < 4; ++r) O[jd][r] *= alpha[r];

        // ---- O += P V : A = P (same-wave LDS reload), B = Vt ----
        __builtin_amdgcn_s_setprio(1);
#pragma unroll
        for (int ks = 0; ks < 2; ++ks) {
          const bf16x8 pa = *(const bf16x8*)(&Ps[wv][sw(l15, ks * 32 + quad * 8)]);
#pragma unroll
          for (int jd = 0; jd < 4; ++jd) {
            const bf16x8 vb = *(const bf16x8*)(&Vt[cb][sw(16 * jd + l15, ks * 32 + quad * 8)]);
            O[jd] = __builtin_amdgcn_mfma_f32_16x16x32_bf16(pa, vb, O[jd], 0, 0, 0);
          }
        }
        __builtin_amdgcn_s_setprio(0);
      }

      // ---- finish staging: V scatter into buf cb^1, then single barrier ----
      if (more) {
        asm volatile("s_waitcnt vmcnt(0)" ::: "memory");  // vreg + K glds landed
#pragma unroll
        for (int e = 0; e < 8; ++e) Vt[cb ^ 1][sw(vdb + e, vkey)] = vreg[e];
      }
      __syncthreads();
    }

    // epilogue: O/l -> bf16 attn ws (C-layout scatter, once per pass)
#pragma unroll
    for (int jd = 0; jd < 4; ++jd) {
#pragma unroll
      for (int r = 0; r < 4; ++r) {
        const int row = qb + 16 * wv + 4 * quad + r;
        attno[(rowBase + row) * DIM + h * DH + 16 * jd + l15] =
            __float2bfloat16(O[jd][r] / l_i[r]);
      }
    }
  }
}

// ---------------------------------------------------------------------------
// Kernel 3a: out = attn @ w_out^T + b_out, both operands pre-bf16, glds
// staging (R1 qkv_gemm_pre structure, no in-loop conversion).
// ---------------------------------------------------------------------------
__global__ __launch_bounds__(256) void out_gemm_pre(
    const short* __restrict__ a,             // (8192, 1024) attn bf16
    const short* __restrict__ wob,           // (1024, 1024) bf16
    const float* __restrict__ bo,            // (1024) fp32
    float* __restrict__ out)                 // (8192, 1024) fp32
{
  __shared__ short As[128 * 32];
  __shared__ short Bs[128 * 32];

  const int t    = threadIdx.x;
  const int lane = t & 63;
  const int wv   = t >> 6;
  const int Mb   = blockIdx.y * 128;
  const int Nb   = blockIdx.x * 128;
  const int wr   = (wv >> 1) * 64;
  const int wc   = (wv & 1) * 64;
  const int l15  = lane & 15;
  const int lq   = lane >> 4;
  const int grow = lane >> 2;
  const int gcol = (lane & 3) * 8;

  f32x4 acc[4][4];
#pragma unroll
  for (int i = 0; i < 4; i++)
#pragma unroll
    for (int j = 0; j < 4; j++) acc[i][j] = (f32x4){0.f, 0.f, 0.f, 0.f};

  for (int k0 = 0; k0 < DIM; k0 += 32) {
    __syncthreads();
#pragma unroll
    for (int it = 0; it < 2; ++it) {
      const int r0 = wv * 32 + it * 16;
      glds16(a   + (size_t)(Mb + r0 + grow) * DIM + k0 + gcol, As + r0 * 32);
      glds16(wob + (size_t)(Nb + r0 + grow) * DIM + k0 + gcol, Bs + r0 * 32);
    }
    __syncthreads();

    bf16x8 af[4], bfr[4];
#pragma unroll
    for (int i = 0; i < 4; i++)
      af[i] = *(const bf16x8*)(As + (wr + i * 16 + l15) * 32 + lq * 8);
#pragma unroll
    for (int j = 0; j < 4; j++)
      bfr[j] = *(const bf16x8*)(Bs + (wc + j * 16 + l15) * 32 + lq * 8);
#pragma unroll
    for (int i = 0; i < 4; i++)
#pragma unroll
      for (int j = 0; j < 4; j++)
        acc[i][j] = __builtin_amdgcn_mfma_f32_16x16x32_bf16(af[i], bfr[j], acc[i][j], 0, 0, 0);
  }

#pragma unroll
  for (int j = 0; j < 4; j++) {
    const int col = Nb + wc + j * 16 + l15;
    const float bias = bo[col];
#pragma unroll
    for (int i = 0; i < 4; i++) {
#pragma unroll
      for (int r = 0; r < 4; r++) {
        const int row = Mb + wr + i * 16 + lq * 4 + r;
        out[(size_t)row * DIM + col] = acc[i][j][r] + bias;
      }
    }
  }
}

// ---------------------------------------------------------------------------
// Kernel 3b (fallback): out = attn @ w_out^T + b_out, fp32 W in-loop cvt.
// ---------------------------------------------------------------------------
__global__ __launch_bounds__(256) void out_gemm(
    const __hip_bfloat16* __restrict__ a,    // (8192, 1024) attn, bf16
    const float* __restrict__ wo,            // (1024, 1024) fp32
    const float* __restrict__ bo,            // (1024) fp32
    float* __restrict__ out)                 // (8192, 1024) fp32
{
  __shared__ short As[128 * 32];
  __shared__ short Bs[128 * 32];

  const int t    = threadIdx.x;
  const int lane = t & 63;
  const int wv   = t >> 6;
  const int Mb   = blockIdx.y * 128;
  const int Nb   = blockIdx.x * 128;
  const int wr   = (wv >> 1) * 64;
  const int wc   = (wv & 1) * 64;
  const int l15  = lane & 15;
  const int lq   = lane >> 4;
  const int srow = wv * 16 + (lane >> 2);
  const int scol = (lane & 3) * 8;

  f32x4 acc[4][4];
#pragma unroll
  for (int i = 0; i < 4; i++)
#pragma unroll
    for (int j = 0; j < 4; j++) acc[i][j] = (f32x4){0.f, 0.f, 0.f, 0.f};

  for (int k0 = 0; k0 < DIM; k0 += 32) {
    bf16x8 areg[2], breg[2];
#pragma unroll
    for (int it = 0; it < 2; ++it) {
      areg[it] = *(const bf16x8*)(a + (size_t)(Mb + it * 64 + srow) * DIM + k0 + scol);
      const float* bp = wo + (size_t)(Nb + it * 64 + srow) * DIM + k0 + scol;
      const float4 b0 = *(const float4*)(bp);
      const float4 b1 = *(const float4*)(bp + 4);
      const float bf8[8] = {b0.x, b0.y, b0.z, b0.w, b1.x, b1.y, b1.z, b1.w};
#pragma unroll
      for (int e = 0; e < 8; e++) breg[it][e] = f2bf(bf8[e]);
    }
    __syncthreads();
#pragma unroll
    for (int it = 0; it < 2; ++it) {
      *(bf16x8*)(As + (it * 64 + srow) * 32 + scol) = areg[it];
      *(bf16x8*)(Bs + (it * 64 + srow) * 32 + scol) = breg[it];
    }
    __syncthreads();

    bf16x8 af[4], bfr[4];
#pragma unroll
    for (int i = 0; i < 4; i++)
      af[i] = *(const bf16x8*)(As + (wr + i * 16 + l15) * 32 + lq * 8);
#pragma unroll
    for (int j = 0; j < 4; j++)
      bfr[j] = *(const bf16x8*)(Bs + (wc + j * 16 + l15) * 32 + lq * 8);
#pragma unroll
    for (int i = 0; i < 4; i++)
#pragma unroll
      for (int j = 0; j < 4; j++)
        acc[i][j] = __builtin_amdgcn_mfma_f32_16x16x32_bf16(af[i], bfr[j], acc[i][j], 0, 0, 0);
  }

#pragma unroll
  for (int j = 0; j < 4; j++) {
    const int col = Nb + wc + j * 16 + l15;
    const float bias = bo[col];
#pragma unroll
    for (int i = 0; i < 4; i++) {
#pragma unroll
      for (int r = 0; r < 4; r++) {
        const int row = Mb + wr + i * 16 + lq * 4 + r;
        out[(size_t)row * DIM + col] = acc[i][j][r] + bias;
      }
    }
  }
}

// ---------------------------------------------------------------------------
extern "C" void kernel_launch(void* const* d_in, const int* in_sizes, int n_in,
                              void* d_out, int out_size, void* d_ws, size_t ws_size,
                              hipStream_t stream) {
  const float* q    = (const float*)d_in[0];
  const float* k    = (const float*)d_in[1];
  const float* v    = (const float*)d_in[2];
  const float* wqkv = (const float*)d_in[3];
  const float* bqkv = (const float*)d_in[4];
  const float* wout = (const float*)d_in[5];
  const float* bout = (const float*)d_in[6];

  // ws layout:
  //   [0,48MB)    qkv_hi bf16 (8192x3072)
  //   [48,96MB)   qkv_lo bf16 (8192x3072; only q,k cols written/read)
  //   [96MB,...)  prep path: A_hi(48) A_lo(48) B_hi(18) B_lo(18) = +132MB
  //               attn bf16 (16MB) aliases A_hi[0:16MB] (A region dead after
  //               qkv_gemm_8p); wout bf16 (2MB) aliases A_hi[16:18MB].
  //   fallback:   attn bf16 at 96MB (112MB total)
  const size_t PLANE = (size_t)MROWS * K3 * 2;        // 50331648 B
  const size_t BPLN  = (size_t)K3 * K3 * 2;           // 18874368 B
  short* qh = (short*)d_ws;
  short* ql = (short*)((char*)d_ws + PLANE);
  char*  p2 = (char*)d_ws + 2 * PLANE;                // offset 96 MB
  __hip_bfloat16* attnws = (__hip_bfloat16*)p2;

  const size_t NEED = 2 * PLANE + 2 * PLANE + 2 * BPLN;  // 228 MB

  if (ws_size >= NEED) {
    short* Ah = (short*)p2;
    short* Al = Ah + (size_t)MROWS * K3;
    short* Bh = Al + (size_t)MROWS * K3;
    short* Bl = Bh + (size_t)K3 * K3;
    short* wob = (short*)(p2 + (size_t)MROWS * DIM * 2);  // after attnws
    prep_x<<<4096, 256, 0, stream>>>(q, k, v, Ah, Al);
    prep_w<<<2048, 256, 0, stream>>>(wqkv, Bh, Bl);
    qkv_gemm_8p<<<dim3(256), 512, 0, stream>>>(Ah, Al, Bh, Bl, bqkv, qh, ql);
    prep_wo<<<256, 256, 0, stream>>>(wout, wob);          // A region now dead
    attn_fwd<<<dim3(512), 512, 0, stream>>>(qh, ql, attnws);
    out_gemm_pre<<<dim3(DIM / 128, MROWS / 128), 256, 0, stream>>>(
        (const short*)attnws, wob, bout, (float*)d_out);
  } else {
    qkv_gemm_fly<<<dim3(K3 / 128, MROWS / 128), 256, 0, stream>>>(
        q, k, v, wqkv, bqkv, qh, ql);
    attn_fwd<<<dim3(512), 512, 0, stream>>>(qh, ql, attnws);
    out_gemm<<<dim3(DIM / 128, MROWS / 128), 256, 0, stream>>>(attnws, wout, bout,
                                                               (float*)d_out);
  }
}